// Round 11
// baseline (578.014 us; speedup 1.0000x reference)
//
#include <hip/hip_runtime.h>
#include <hip/hip_bf16.h>

#define B_    16
#define L_    190
#define LP_   192        // padded L
#define DM_   512
#define DI_   1024
#define LB_   3040       // B_*L_
#define RT_   6080       // 2*LB_ rows (dir-major)
#define LBDI_ 3112960    // LB_*DI_

typedef __attribute__((ext_vector_type(8))) short bf16x8;
typedef __attribute__((ext_vector_type(4))) float f32x4;
typedef __attribute__((ext_vector_type(4))) unsigned short u16x4;

typedef const __attribute__((address_space(1))) void gvoid;
typedef __attribute__((address_space(3))) void lvoid;
#define LOAD_LDS16(g, l) __builtin_amdgcn_global_load_lds((gvoid*)(g), (lvoid*)(l), 16, 0, 0)

__device__ __forceinline__ float siluf(float v) { return v / (1.f + __expf(-v)); }
__device__ __forceinline__ float softplusf(float v) {
  return v > 0.f ? v + log1pf(__expf(-v)) : log1pf(__expf(v));
}
__device__ __forceinline__ float bf2f(unsigned short u) {
  unsigned int w = (unsigned int)u << 16; return __builtin_bit_cast(float, w);
}

// ---------------------------------------------------------------------------
// f32 -> padded bf16 (segments 0-8); segment 9 = pc_mask convert + bias pads.
struct Cvt2 { const float* src; __hip_bfloat16* dst; int R, C, Rp, Cp; };
struct CvtPack2 { Cvt2 d[9]; };

__global__ __launch_bounds__(256) void cvt_all3(CvtPack2 p,
    const void* __restrict__ pcm, float* __restrict__ maskf,
    const float* __restrict__ irb, const float* __restrict__ orb,
    float* __restrict__ b_inrs, float* __restrict__ b_outrs)
{
  if (blockIdx.y == 9) {
    __shared__ int votes[3];
    if (threadIdx.x < 3) votes[threadIdx.x] = 0;
    __syncthreads();
    if (threadIdx.x < 48) {
      int idx = threadIdx.x * 191;
      const unsigned char* p8  = (const unsigned char*)pcm;
      const unsigned int*  p32 = (const unsigned int*)pcm;
      if (p8[idx] == 1) atomicAdd(&votes[0], 1);
      unsigned int v = p32[idx];
      if (v == 1u)          atomicAdd(&votes[1], 1);
      if (v == 0x3f800000u) atomicAdd(&votes[2], 1);
    }
    __syncthreads();
    int mode = (votes[0] >= 48) ? 0 : (votes[1] >= 48 ? 1 : (votes[2] >= 48 ? 2 : 0));
    for (int i = blockIdx.x * 256 + threadIdx.x; i < L_ * LP_; i += gridDim.x * 256) {
      int r = i / LP_, c = i % LP_;
      float v = 0.f;
      if (c < L_) {
        int s = r * L_ + c;
        if (mode == 0)      v = ((const unsigned char*)pcm)[s] ? 1.f : 0.f;
        else if (mode == 1) v = ((const int*)pcm)[s] ? 1.f : 0.f;
        else                v = ((const float*)pcm)[s];
      }
      maskf[i] = v;
    }
    if (blockIdx.x == 0 && threadIdx.x < LP_) {
      b_inrs[threadIdx.x]  = (threadIdx.x < L_) ? irb[threadIdx.x] : 0.f;
      b_outrs[threadIdx.x] = (threadIdx.x < L_) ? orb[threadIdx.x] : 0.f;
    }
    return;
  }
  Cvt2 D = p.d[blockIdx.y];
  int n = D.Rp * D.Cp;
  if (D.C == D.Cp) {
    int nsrc = D.R * D.C;
    for (int i4 = (blockIdx.x * 256 + threadIdx.x) * 4; i4 < n; i4 += gridDim.x * 256 * 4) {
      __hip_bfloat16 o[4];
      if (i4 + 3 < nsrc) {
        f32x4 v = *(const f32x4*)(D.src + i4);
        #pragma unroll
        for (int q = 0; q < 4; ++q) o[q] = __float2bfloat16(v[q]);
      } else {
        #pragma unroll
        for (int q = 0; q < 4; ++q) { int i = i4 + q; o[q] = __float2bfloat16(i < nsrc ? D.src[i] : 0.f); }
      }
      *(u16x4*)(D.dst + i4) = *(u16x4*)o;
    }
  } else {
    for (int i = blockIdx.x * 256 + threadIdx.x; i < n; i += gridDim.x * 256) {
      int r = i / D.Cp, c = i - r * D.Cp;
      float v = (r < D.R && c < D.C) ? D.src[(size_t)r * D.C + c] : 0.f;
      D.dst[i] = __float2bfloat16(v);
    }
  }
}

// ---------------------------------------------------------------------------
// MFMA GEMM 128x128 (4 waves x 64x64). EPI: 0 none | 1 +bias | 2 (+bias)*aux |
// 3 softplus | 4 (+bias)*aux[(m%190)*N+n]
template<int EPI, bool OF32, bool OBF>
__global__ __launch_bounds__(256) void gemm128(
    const __hip_bfloat16* __restrict__ A, int lda, int M,
    const __hip_bfloat16* __restrict__ Bw, int Brows,
    const float* __restrict__ bias, const float* __restrict__ aux,
    float* __restrict__ Cf, __hip_bfloat16* __restrict__ Cb,
    int N, int K)
{
  __shared__ bf16x8 SA[2][512];
  __shared__ bf16x8 SB[2][512];
  const int tid = threadIdx.x;
  const int wave = tid >> 6, lane = tid & 63;
  const int m0 = blockIdx.y * 128, n0 = blockIdx.x * 128;
  const int wm = (wave >> 1) * 64, wn = (wave & 1) * 64;
  const int l15 = lane & 15, lkb = lane >> 4;

  f32x4 acc[4][4] = {};

  auto stage = [&](int bsel, int k0) {
    #pragma unroll
    for (int it = 0; it < 2; ++it) {
      int c = it * 256 + tid;
      int row = c & 127, kb = c >> 7;
      int ar = m0 + row; ar = ar < M ? ar : M - 1;
      const __hip_bfloat16* ga = A + (size_t)ar * lda + (k0 + kb * 8);
      LOAD_LDS16(ga, &SA[bsel][it * 256 + wave * 64]);
      int br = n0 + row; br = br < Brows ? br : Brows - 1;
      const __hip_bfloat16* gb = Bw + (size_t)br * K + (k0 + kb * 8);
      LOAD_LDS16(gb, &SB[bsel][it * 256 + wave * 64]);
    }
  };

  const int nk = K >> 5;
  stage(0, 0);
  __syncthreads();
  int buf = 0;
  for (int kt = 0; kt < nk; ++kt) {
    if (kt + 1 < nk) stage(buf ^ 1, (kt + 1) * 32);
    bf16x8 af[4], bq[4];
    #pragma unroll
    for (int f = 0; f < 4; ++f) {
      af[f] = SA[buf][lkb * 128 + wm + f * 16 + l15];
      bq[f] = SB[buf][lkb * 128 + wn + f * 16 + l15];
    }
    #pragma unroll
    for (int i = 0; i < 4; ++i)
      #pragma unroll
      for (int j = 0; j < 4; ++j)
        acc[i][j] = __builtin_amdgcn_mfma_f32_16x16x32_bf16(af[i], bq[j], acc[i][j], 0, 0, 0);
    __syncthreads();
    buf ^= 1;
  }

  #pragma unroll
  for (int i = 0; i < 4; ++i) {
    int r0 = m0 + wm + i * 16 + (lkb << 2);
    #pragma unroll
    for (int j = 0; j < 4; ++j) {
      int col = n0 + wn + j * 16 + l15;
      if (col >= N) continue;
      #pragma unroll
      for (int r = 0; r < 4; ++r) {
        int row = r0 + r;
        if (row >= M) continue;
        float v = acc[i][j][r];
        if (EPI >= 1) v += bias[col];
        if (EPI == 2) v *= aux[(size_t)row * N + col];
        if (EPI == 3) v = softplusf(v);
        if (EPI == 4) v *= aux[(size_t)(row % L_) * N + col];
        if (OF32) Cf[(size_t)row * N + col] = v;
        if (OBF)  Cb[(size_t)row * N + col] = __float2bfloat16(v);
      }
    }
  }
}

// ---------------------------------------------------------------------------
// MFMA GEMM 64x64 (4 waves x 32x32) — for small-N / latency-bound links.
template<int EPI, bool OF32, bool OBF>
__global__ __launch_bounds__(256) void gemm64(
    const __hip_bfloat16* __restrict__ A, int lda, int M,
    const __hip_bfloat16* __restrict__ Bw, int Brows,
    const float* __restrict__ bias, const float* __restrict__ aux,
    float* __restrict__ Cf, __hip_bfloat16* __restrict__ Cb,
    int N, int K)
{
  __shared__ bf16x8 SA[2][256];
  __shared__ bf16x8 SB[2][256];
  const int tid = threadIdx.x;
  const int wave = tid >> 6, lane = tid & 63;
  const int m0 = blockIdx.y * 64, n0 = blockIdx.x * 64;
  const int wm = (wave >> 1) * 32, wn = (wave & 1) * 32;
  const int l15 = lane & 15, lkb = lane >> 4;

  f32x4 acc[2][2] = {};

  auto stage = [&](int bsel, int k0) {
    int row = tid & 63, kb = tid >> 6;
    int ar = m0 + row; ar = ar < M ? ar : M - 1;
    const __hip_bfloat16* ga = A + (size_t)ar * lda + (k0 + kb * 8);
    LOAD_LDS16(ga, &SA[bsel][wave * 64]);
    int br = n0 + row; br = br < Brows ? br : Brows - 1;
    const __hip_bfloat16* gb = Bw + (size_t)br * K + (k0 + kb * 8);
    LOAD_LDS16(gb, &SB[bsel][wave * 64]);
  };

  const int nk = K >> 5;
  stage(0, 0);
  __syncthreads();
  int buf = 0;
  for (int kt = 0; kt < nk; ++kt) {
    if (kt + 1 < nk) stage(buf ^ 1, (kt + 1) * 32);
    bf16x8 af[2], bq[2];
    #pragma unroll
    for (int f = 0; f < 2; ++f) {
      af[f] = SA[buf][lkb * 64 + wm + f * 16 + l15];
      bq[f] = SB[buf][lkb * 64 + wn + f * 16 + l15];
    }
    #pragma unroll
    for (int i = 0; i < 2; ++i)
      #pragma unroll
      for (int j = 0; j < 2; ++j)
        acc[i][j] = __builtin_amdgcn_mfma_f32_16x16x32_bf16(af[i], bq[j], acc[i][j], 0, 0, 0);
    __syncthreads();
    buf ^= 1;
  }

  #pragma unroll
  for (int i = 0; i < 2; ++i) {
    int r0 = m0 + wm + i * 16 + (lkb << 2);
    #pragma unroll
    for (int j = 0; j < 2; ++j) {
      int col = n0 + wn + j * 16 + l15;
      if (col >= N) continue;
      #pragma unroll
      for (int r = 0; r < 4; ++r) {
        int row = r0 + r;
        if (row >= M) continue;
        float v = acc[i][j][r];
        if (EPI >= 1) v += bias[col];
        if (EPI == 2) v *= aux[(size_t)row * N + col];
        if (EPI == 3) v = softplusf(v);
        if (EPI == 4) v *= aux[(size_t)(row % L_) * N + col];
        if (OF32) Cf[(size_t)row * N + col] = v;
        if (OBF)  Cb[(size_t)row * N + col] = __float2bfloat16(v);
      }
    }
  }
}

// ---------------------------------------------------------------------------
// out_proj GEMM with fused A-operand: A[m][k] = (y_f+y_b)*silu(z) on the fly.
// Reg-stage A (3 loads + VALU + ds_write); B staged via global_load_lds.
__global__ __launch_bounds__(256) void gemm64_yz(
    const __hip_bfloat16* __restrict__ Y,   // [2][LB_][DI_] bf16 (y_f, y_b)
    const __hip_bfloat16* __restrict__ Xz,  // [LB_][2*DI_]  bf16 (z at +DI_)
    const __hip_bfloat16* __restrict__ Bw,  // [512][1024]
    __hip_bfloat16* __restrict__ Cb,        // [LB_][512]
    int M, int N, int K)
{
  __shared__ bf16x8 SA[2][256];
  __shared__ bf16x8 SB[2][256];
  const int tid = threadIdx.x;
  const int wave = tid >> 6, lane = tid & 63;
  const int m0 = blockIdx.y * 64, n0 = blockIdx.x * 64;
  const int wm = (wave >> 1) * 32, wn = (wave & 1) * 32;
  const int l15 = lane & 15, lkb = lane >> 4;

  f32x4 acc[2][2] = {};

  auto stage = [&](int bsel, int k0) {
    int row = tid & 63, kb = tid >> 6;
    int ar = m0 + row; ar = ar < M ? ar : M - 1;
    size_t o = (size_t)ar * DI_ + (k0 + kb * 8);
    u16x4 f0 = *(const u16x4*)(Y + o);
    u16x4 f1 = *(const u16x4*)(Y + o + 4);
    u16x4 g0 = *(const u16x4*)(Y + LBDI_ + o);
    u16x4 g1 = *(const u16x4*)(Y + LBDI_ + o + 4);
    size_t zo = (size_t)ar * (2 * DI_) + DI_ + (k0 + kb * 8);
    u16x4 z0 = *(const u16x4*)(Xz + zo);
    u16x4 z1 = *(const u16x4*)(Xz + zo + 4);
    unsigned short av[8];
    #pragma unroll
    for (int q = 0; q < 4; ++q) {
      float v = (bf2f(f0[q]) + bf2f(g0[q])) * siluf(bf2f(z0[q]));
      av[q] = __bfloat16_as_ushort(__float2bfloat16(v));
      float w = (bf2f(f1[q]) + bf2f(g1[q])) * siluf(bf2f(z1[q]));
      av[q + 4] = __bfloat16_as_ushort(__float2bfloat16(w));
    }
    SA[bsel][wave * 64 + row] = *(bf16x8*)av;
    int br = n0 + row; br = br < N ? br : N - 1;
    const __hip_bfloat16* gb = Bw + (size_t)br * K + (k0 + kb * 8);
    LOAD_LDS16(gb, &SB[bsel][wave * 64]);
  };

  const int nk = K >> 5;
  stage(0, 0);
  __syncthreads();
  int buf = 0;
  for (int kt = 0; kt < nk; ++kt) {
    if (kt + 1 < nk) stage(buf ^ 1, (kt + 1) * 32);
    bf16x8 af[2], bq[2];
    #pragma unroll
    for (int f = 0; f < 2; ++f) {
      af[f] = SA[buf][lkb * 64 + wm + f * 16 + l15];
      bq[f] = SB[buf][lkb * 64 + wn + f * 16 + l15];
    }
    #pragma unroll
    for (int i = 0; i < 2; ++i)
      #pragma unroll
      for (int j = 0; j < 2; ++j)
        acc[i][j] = __builtin_amdgcn_mfma_f32_16x16x32_bf16(af[i], bq[j], acc[i][j], 0, 0, 0);
    __syncthreads();
    buf ^= 1;
  }

  #pragma unroll
  for (int i = 0; i < 2; ++i) {
    int r0 = m0 + wm + i * 16 + (lkb << 2);
    #pragma unroll
    for (int j = 0; j < 2; ++j) {
      int col = n0 + wn + j * 16 + l15;
      if (col >= N) continue;
      #pragma unroll
      for (int r = 0; r < 4; ++r) {
        int row = r0 + r;
        if (row >= M) continue;
        Cb[(size_t)row * N + col] = __float2bfloat16(acc[i][j][r]);
      }
    }
  }
}

// ---------------------------------------------------------------------------
// Depthwise conv(k=4) + bias + silu, both directions; 4 channels per thread.
__global__ __launch_bounds__(256) void conv_silu(
    const __hip_bfloat16* __restrict__ xz, const float* __restrict__ w,
    const float* __restrict__ cb, __hip_bfloat16* __restrict__ xcbf)
{
  int t = blockIdx.x * 256 + threadIdx.x;
  int c4 = (t & (DI_ / 4 - 1)) * 4;
  int bl = t >> 8;
  int l = bl % L_;
  int b = bl / L_;
  const __hip_bfloat16* base = xz + (size_t)b * L_ * (2 * DI_) + c4;
  float xr[7][4];
  #pragma unroll
  for (int j = 0; j < 7; ++j) {
    int gl = l + j - 3;
    if (gl >= 0 && gl < L_) {
      u16x4 v = *(const u16x4*)(base + (size_t)gl * (2 * DI_));
      #pragma unroll
      for (int q = 0; q < 4; ++q) xr[j][q] = bf2f(v[q]);
    } else {
      #pragma unroll
      for (int q = 0; q < 4; ++q) xr[j][q] = 0.f;
    }
  }
  __hip_bfloat16 of[4], ob[4];
  #pragma unroll
  for (int q = 0; q < 4; ++q) {
    int c = c4 + q;
    float w0 = w[c * 4], w1 = w[c * 4 + 1], w2 = w[c * 4 + 2], w3 = w[c * 4 + 3];
    float bias = cb[c];
    float sf = fmaf(w0, xr[0][q], fmaf(w1, xr[1][q], fmaf(w2, xr[2][q], fmaf(w3, xr[3][q], bias))));
    float sb = fmaf(w0, xr[6][q], fmaf(w1, xr[5][q], fmaf(w2, xr[4][q], fmaf(w3, xr[3][q], bias))));
    of[q] = __float2bfloat16(siluf(sf));
    ob[q] = __float2bfloat16(siluf(sb));
  }
  size_t o = (size_t)bl * DI_ + c4;
  *(u16x4*)(xcbf + o)         = *(u16x4*)of;
  *(u16x4*)(xcbf + LBDI_ + o) = *(u16x4*)ob;
}

// ---------------------------------------------------------------------------
// Selective scan v10: v9 + packed dt/xc register cache (24 u32) so pass 2
// does ZERO dt/xc global reads. 32 d x 8 chunks of 24. Grid (32,16,2).
#define SCT_ 24
#define HS_  17        // padded state stride for sH
__global__ __launch_bounds__(256) void scan_v10(
    const __hip_bfloat16* __restrict__ dtb, // [RT_][DI_] bf16
    const float* __restrict__ xd,           // [RT_][64]  f32
    const __hip_bfloat16* __restrict__ xc,  // [RT_][DI_] bf16
    const float* __restrict__ A_log, const float* __restrict__ Dv,
    __hip_bfloat16* __restrict__ y)         // [RT_][DI_] bf16
{
  __shared__ float sH[256 * HS_];    // 17408 B
  __shared__ float sS[256];          //  1024 B

  const int tid   = threadIdx.x;
  const int dl    = tid & 31;
  const int chunk = tid >> 5;
  const int dglob = blockIdx.x * 32 + dl;
  const int b     = blockIdx.y;
  const int dir   = blockIdx.z;
  const int rowbase = dir * LB_ + b * L_;
  const unsigned short* xcu = (const unsigned short*)xc;
  const unsigned short* dtu = (const unsigned short*)dtb;
  const float* Arow = A_log + dglob * 16;

  // A[s] = -exp(A_log[s]); detect A[s] == (s+1)*A0 (harness: A_log=log(1..16))
  const float A0 = -__expf(Arow[0]);
  bool fast = true;
  #pragma unroll
  for (int s = 1; s < 16; ++s) {
    float As = -__expf(Arow[s]);
    fast = fast && (fabsf(As - (float)(s + 1) * A0) <= 1e-4f * (float)(s + 1));
  }
  const float Dd = Dv[dglob];
  const int cstart = chunk * SCT_;

  // log-depth powers: ep[s] = e1^(s+1), crit path 4 dependent muls
  auto powers = [&](float e1, float* ep) {
    ep[0] = e1;
    #pragma unroll
    for (int s = 1; s < 16; ++s) ep[s] = ep[(s - 1) >> 1] * ep[s >> 1];
  };

  // ---- pass 1: local scan from 0; cache packed (dt,xc) ----
  unsigned int pk[SCT_];
  float h[16];
  #pragma unroll
  for (int s = 0; s < 16; ++s) h[s] = 0.f;
  float dsum = 0.f;
  #pragma unroll
  for (int k = 0; k < SCT_; ++k) {
    int l = cstart + k;
    bool valid = l < L_;
    int pos = dir ? (L_ - 1 - l) : l;
    pos = valid ? pos : 0;
    size_t grow = (size_t)(rowbase + pos);
    unsigned short du16 = valid ? dtu[grow * DI_ + dglob] : (unsigned short)0;
    unsigned short xu16 = valid ? xcu[grow * DI_ + dglob] : (unsigned short)0;
    pk[k] = ((unsigned int)du16 << 16) | xu16;
    float dtv = bf2f(du16);
    float xcv = bf2f(xu16);
    float du  = dtv * xcv;
    dsum += dtv;
    const float* brow = xd + grow * 64;
    f32x4 bq0 = *(const f32x4*)(brow + 32);
    f32x4 bq1 = *(const f32x4*)(brow + 36);
    f32x4 bq2 = *(const f32x4*)(brow + 40);
    f32x4 bq3 = *(const f32x4*)(brow + 44);
    float ep[16];
    if (fast) {
      powers(__expf(dtv * A0), ep);
    } else {
      #pragma unroll
      for (int s = 0; s < 16; ++s) ep[s] = __expf(dtv * -__expf(Arow[s]));
    }
    #pragma unroll
    for (int s = 0; s < 16; ++s) {
      float Bv = (s < 4) ? bq0[s & 3] : (s < 8) ? bq1[s & 3] : (s < 12) ? bq2[s & 3] : bq3[s & 3];
      h[s] = fmaf(ep[s], h[s], du * Bv);   // invalid: du=0, ep=1 -> h unchanged
    }
  }
  {
    float* hr = sH + tid * HS_;
    #pragma unroll
    for (int s = 0; s < 16; ++s) hr[s] = h[s];
    sS[tid] = dsum;
  }
  __syncthreads();

  // ---- combine: h_in = fold over previous chunks ----
  float hin[16];
  #pragma unroll
  for (int s = 0; s < 16; ++s) hin[s] = 0.f;
  for (int c = 0; c < chunk; ++c) {
    float S = sS[c * 32 + dl];
    const float* hp = sH + (c * 32 + dl) * HS_;
    float ep[16];
    if (fast) {
      powers(__expf(A0 * S), ep);
    } else {
      #pragma unroll
      for (int s = 0; s < 16; ++s) ep[s] = __expf(-__expf(Arow[s]) * S);
    }
    #pragma unroll
    for (int s = 0; s < 16; ++s)
      hin[s] = fmaf(ep[s], hin[s], hp[s]);
  }

  // ---- pass 2: re-scan from registers, emit y (no dt/xc reads) ----
  #pragma unroll
  for (int s = 0; s < 16; ++s) h[s] = hin[s];
  #pragma unroll
  for (int k = 0; k < SCT_; ++k) {
    int l = cstart + k;
    bool valid = l < L_;
    int pos = dir ? (L_ - 1 - l) : l;
    pos = valid ? pos : 0;
    size_t grow = (size_t)(rowbase + pos);
    float dtv = bf2f((unsigned short)(pk[k] >> 16));
    float xcv = bf2f((unsigned short)(pk[k] & 0xFFFFu));
    float du  = dtv * xcv;
    const float* brow = xd + grow * 64;
    f32x4 bq0 = *(const f32x4*)(brow + 32);
    f32x4 bq1 = *(const f32x4*)(brow + 36);
    f32x4 bq2 = *(const f32x4*)(brow + 40);
    f32x4 bq3 = *(const f32x4*)(brow + 44);
    f32x4 cq0 = *(const f32x4*)(brow + 48);
    f32x4 cq1 = *(const f32x4*)(brow + 52);
    f32x4 cq2 = *(const f32x4*)(brow + 56);
    f32x4 cq3 = *(const f32x4*)(brow + 60);
    float ep[16];
    if (fast) {
      powers(__expf(dtv * A0), ep);
    } else {
      #pragma unroll
      for (int s = 0; s < 16; ++s) ep[s] = __expf(dtv * -__expf(Arow[s]));
    }
    float acc = 0.f;
    #pragma unroll
    for (int s = 0; s < 16; ++s) {
      float Bv = (s < 4) ? bq0[s & 3] : (s < 8) ? bq1[s & 3] : (s < 12) ? bq2[s & 3] : bq3[s & 3];
      float Cv = (s < 4) ? cq0[s & 3] : (s < 8) ? cq1[s & 3] : (s < 12) ? cq2[s & 3] : cq3[s & 3];
      h[s] = fmaf(ep[s], h[s], du * Bv);
      acc  = fmaf(h[s], Cv, acc);
    }
    if (valid)
      y[grow * DI_ + dglob] = __float2bfloat16(fmaf(xcv, Dd, acc));
  }
}

// ---------------------------------------------------------------------------
// tanh-LayerNorm over (L, D) per batch.
__global__ __launch_bounds__(256) void ln_partial(const float* __restrict__ x,
                                                  float* __restrict__ partials)
{
  int b = blockIdx.y, ch = blockIdx.x;
  const float* xb = x + (size_t)b * (L_ * DM_);
  int lo = ch * 12160, hi = lo + 12160;
  float s = 0.f, s2 = 0.f;
  for (int i = lo + threadIdx.x; i < hi; i += 256) {
    float t = tanhf(xb[i]);
    s += t; s2 = fmaf(t, t, s2);
  }
  #pragma unroll
  for (int off = 32; off > 0; off >>= 1) { s += __shfl_down(s, off); s2 += __shfl_down(s2, off); }
  __shared__ float rs[4], rs2[4];
  int wid = threadIdx.x >> 6, lane = threadIdx.x & 63;
  if (lane == 0) { rs[wid] = s; rs2[wid] = s2; }
  __syncthreads();
  if (threadIdx.x == 0) {
    partials[(b * 8 + ch) * 2 + 0] = rs[0] + rs[1] + rs[2] + rs[3];
    partials[(b * 8 + ch) * 2 + 1] = rs2[0] + rs2[1] + rs2[2] + rs2[3];
  }
}

__global__ __launch_bounds__(256) void ln_final(const float* __restrict__ x,
    const float* __restrict__ partials,
    const float* __restrict__ nw, const float* __restrict__ nb,
    float* __restrict__ out)
{
  int b = blockIdx.y, ch = blockIdx.x;
  float S = 0.f, S2 = 0.f;
  #pragma unroll
  for (int i = 0; i < 8; ++i) { S += partials[(b * 8 + i) * 2 + 0]; S2 += partials[(b * 8 + i) * 2 + 1]; }
  const float inv = 1.f / (float)(L_ * DM_);
  float mu = S * inv;
  float var = S2 * inv - mu * mu;
  float r = rsqrtf(var + 1e-5f);
  const float* xb = x + (size_t)b * (L_ * DM_);
  float* ob = out + (size_t)b * (L_ * DM_);
  int lo = ch * 12160, hi = lo + 12160;
  for (int i = lo + threadIdx.x; i < hi; i += 256) {
    float t = tanhf(xb[i]);
    ob[i] = fmaf((t - mu) * r, nw[i], nb[i]);
  }
}

// ---------------------------------------------------------------------------
extern "C" void kernel_launch(void* const* d_in, const int* in_sizes, int n_in,
                              void* d_out, int out_size, void* d_ws, size_t ws_size,
                              hipStream_t stream)
{
  const float* x            = (const float*)d_in[0];
  const void*  pc_mask      = d_in[1];
  const float* in_resize_w  = (const float*)d_in[2];
  const float* in_resize_b  = (const float*)d_in[3];
  const float* in_reset_w   = (const float*)d_in[4];
  const float* in_reset_b   = (const float*)d_in[5];
  const float* out_resize_w = (const float*)d_in[6];
  const float* out_resize_b = (const float*)d_in[7];
  const float* out_reset_w  = (const float*)d_in[8];
  const float* out_reset_b  = (const float*)d_in[9];
  const float* in_proj_w    = (const float*)d_in[10];
  const float* conv_w       = (const float*)d_in[11];
  const float* conv_b       = (const float*)d_in[12];
  const float* x_proj_w     = (const float*)d_in[13];
  const float* dt_proj_w    = (const float*)d_in[14];
  const float* dt_proj_b    = (const float*)d_in[15];
  const float* A_log        = (const float*)d_in[16];
  const float* Dv           = (const float*)d_in[17];
  const float* out_proj_w   = (const float*)d_in[18];
  const float* norm_w       = (const float*)d_in[19];
  const float* norm_b       = (const float*)d_in[20];

  // ---- workspace layout ----
  float* W = (float*)d_ws;
  float* maskf    = W + 0;         // 190*192 = 36480
  float* b_inrs   = W + 36480;     // 192
  float* b_outrs  = W + 36672;     // 192
  float* xd       = W + 36864;     // 6080*64 = 389120 (row-major f32)
  float* partials = W + 425984;    // 256
  __hip_bfloat16* BF = (__hip_bfloat16*)(W + 426240);
  __hip_bfloat16* w_inrs  = BF + 0;         // 192*512
  __hip_bfloat16* w_inrt  = BF + 98304;     // 512*192
  __hip_bfloat16* w_inpj  = BF + 196608;    // 2048*512
  __hip_bfloat16* w_xpj   = BF + 1245184;   // 64*1024
  __hip_bfloat16* w_dtpj  = BF + 1310720;   // 1024*32
  __hip_bfloat16* w_outpj = BF + 1343488;   // 512*1024
  __hip_bfloat16* w_outrs = BF + 1867776;   // 192*512
  __hip_bfloat16* w_outrt = BF + 1966080;   // 512*192
  __hip_bfloat16* x_bf    = BF + 2064384;   // 3040*512
  __hip_bfloat16* h1_bf   = BF + 3620864;   // 3040*192
  __hip_bfloat16* h_bf    = BF + 4204544;   // 3040*512
  __hip_bfloat16* xz_bf   = BF + 5761024;   // 3040*2048
  __hip_bfloat16* xc_bf   = BF + 11986944;  // 2*3040*1024
  __hip_bfloat16* y_bf    = BF + 18212864;  // 6080*1024
  __hip_bfloat16* xd_bf   = BF + 24438784;  // 6080*64
  __hip_bfloat16* dt_bf   = BF + 24827904;  // 6080*1024
  __hip_bfloat16* o_pre   = BF + 31053824;  // 3040*512
  __hip_bfloat16* o2_bf   = BF + 32610304;  // 3040*192

  float* out_ln = (float*)d_out;
  float* out_o  = (float*)d_out + (size_t)LB_ * DM_;

  dim3 blk(256);

  CvtPack2 P;
  P.d[0] = Cvt2{ x,            x_bf,    3040, 512, 3040, 512 };
  P.d[1] = Cvt2{ in_resize_w,  w_inrs,  190, 512, 192, 512 };
  P.d[2] = Cvt2{ in_reset_w,   w_inrt,  512, 190, 512, 192 };
  P.d[3] = Cvt2{ in_proj_w,    w_inpj,  2048, 512, 2048, 512 };
  P.d[4] = Cvt2{ x_proj_w,     w_xpj,   64, 1024, 64, 1024 };
  P.d[5] = Cvt2{ dt_proj_w,    w_dtpj,  1024, 32, 1024, 32 };
  P.d[6] = Cvt2{ out_proj_w,   w_outpj, 512, 1024, 512, 1024 };
  P.d[7] = Cvt2{ out_resize_w, w_outrs, 190, 512, 192, 512 };
  P.d[8] = Cvt2{ out_reset_w,  w_outrt, 512, 190, 512, 192 };
  cvt_all3<<<dim3(256, 10), blk, 0, stream>>>(P, pc_mask, maskf,
      in_resize_b, out_resize_b, b_inrs, b_outrs);

  // h1 = x @ in_resize_w^T + b                       (m[0,0]==1: diag of eye)
  gemm64<1,false,true><<<dim3(3,48), blk, 0, stream>>>(x_bf, 512, 3040, w_inrs, 192, b_inrs, nullptr, nullptr, h1_bf, LP_, 512);
  // h = (h1 @ in_reset_w^T + b) * x
  gemm64<2,false,true><<<dim3(8,48), blk, 0, stream>>>(h1_bf, LP_, 3040, w_inrt, 512, in_reset_b, x, nullptr, h_bf, 512, LP_);
  // xz = h @ in_proj_w^T
  gemm128<0,false,true><<<dim3(16,24), blk, 0, stream>>>(h_bf, 512, 3040, w_inpj, 2048, nullptr, nullptr, nullptr, xz_bf, 2048, 512);
  // conv + silu (both dirs)
  conv_silu<<<dim3(LBDI_/1024), blk, 0, stream>>>(xz_bf, conv_w, conv_b, xc_bf);
  // x_dbl = xc @ x_proj_w^T  (both dirs, M=6080); f32 + bf16 row-major
  gemm64<0,true,true><<<dim3(1,95), blk, 0, stream>>>(xc_bf, 1024, 6080, w_xpj, 64, nullptr, nullptr, xd, xd_bf, 64, 1024);
  // dt = softplus(x_dbl[:,:32] @ dt_proj_w^T + b) -> bf16
  gemm64<3,false,true><<<dim3(16,95), blk, 0, stream>>>(xd_bf, 64, 6080, w_dtpj, 1024, dt_proj_b, nullptr, nullptr, dt_bf, 1024, 32);
  // selective scan (packed register cache, single dt/xc read)
  scan_v10<<<dim3(32, 16, 2), blk, 0, stream>>>(dt_bf, xd, xc_bf, A_log, Dv, y_bf);
  // o_pre = ((y_f+y_b)*silu(z)) @ out_proj_w^T   (fused combine)
  gemm64_yz<<<dim3(8,48), blk, 0, stream>>>(y_bf, xz_bf, w_outpj, o_pre, 3040, 512, 1024);
  // o2 = (o_pre @ out_resize_w^T + b) * mask[l,:]
  gemm64<4,false,true><<<dim3(3,48), blk, 0, stream>>>(o_pre, 512, 3040, w_outrs, 192, b_outrs, maskf, nullptr, o2_bf, LP_, 512);
  // o = (o2 @ out_reset_w^T + b) * x  -> output 1
  gemm64<2,true,false><<<dim3(8,48), blk, 0, stream>>>(o2_bf, LP_, 3040, w_outrt, 512, out_reset_b, x, out_o, nullptr, 512, LP_);
  // output 0: layernorm(tanh(x))
  dim3 lgrid(8, B_);
  ln_partial<<<lgrid, blk, 0, stream>>>(x, partials);
  ln_final<<<lgrid, blk, 0, stream>>>(x, partials, norm_w, norm_b, out_ln);
}

// Round 12
// 274.132 us; speedup vs baseline: 2.1085x; 2.1085x over previous
//
#include <hip/hip_runtime.h>
#include <hip/hip_bf16.h>

#define B_    16
#define L_    190
#define LP_   192        // padded L
#define DM_   512
#define DI_   1024
#define LB_   3040       // B_*L_
#define RT_   6080       // 2*LB_ rows (dir-major)
#define LBDI_ 3112960    // LB_*DI_

typedef __attribute__((ext_vector_type(8))) short bf16x8;
typedef __attribute__((ext_vector_type(4))) float f32x4;
typedef __attribute__((ext_vector_type(4))) unsigned short u16x4;

typedef const __attribute__((address_space(1))) void gvoid;
typedef __attribute__((address_space(3))) void lvoid;
#define LOAD_LDS16(g, l) __builtin_amdgcn_global_load_lds((gvoid*)(g), (lvoid*)(l), 16, 0, 0)

__device__ __forceinline__ float siluf(float v) { return v / (1.f + __expf(-v)); }
__device__ __forceinline__ float softplusf(float v) {
  return v > 0.f ? v + log1pf(__expf(-v)) : log1pf(__expf(v));
}
__device__ __forceinline__ float bf2f(unsigned short u) {
  unsigned int w = (unsigned int)u << 16; return __builtin_bit_cast(float, w);
}

// ---------------------------------------------------------------------------
// f32 -> padded bf16 (segments 0-8); segment 9 = pc_mask convert + bias pads.
struct Cvt2 { const float* src; __hip_bfloat16* dst; int R, C, Rp, Cp; };
struct CvtPack2 { Cvt2 d[9]; };

__global__ __launch_bounds__(256) void cvt_all3(CvtPack2 p,
    const void* __restrict__ pcm, float* __restrict__ maskf,
    const float* __restrict__ irb, const float* __restrict__ orb,
    float* __restrict__ b_inrs, float* __restrict__ b_outrs)
{
  if (blockIdx.y == 9) {
    __shared__ int votes[3];
    if (threadIdx.x < 3) votes[threadIdx.x] = 0;
    __syncthreads();
    if (threadIdx.x < 48) {
      int idx = threadIdx.x * 191;
      const unsigned char* p8  = (const unsigned char*)pcm;
      const unsigned int*  p32 = (const unsigned int*)pcm;
      if (p8[idx] == 1) atomicAdd(&votes[0], 1);
      unsigned int v = p32[idx];
      if (v == 1u)          atomicAdd(&votes[1], 1);
      if (v == 0x3f800000u) atomicAdd(&votes[2], 1);
    }
    __syncthreads();
    int mode = (votes[0] >= 48) ? 0 : (votes[1] >= 48 ? 1 : (votes[2] >= 48 ? 2 : 0));
    for (int i = blockIdx.x * 256 + threadIdx.x; i < L_ * LP_; i += gridDim.x * 256) {
      int r = i / LP_, c = i % LP_;
      float v = 0.f;
      if (c < L_) {
        int s = r * L_ + c;
        if (mode == 0)      v = ((const unsigned char*)pcm)[s] ? 1.f : 0.f;
        else if (mode == 1) v = ((const int*)pcm)[s] ? 1.f : 0.f;
        else                v = ((const float*)pcm)[s];
      }
      maskf[i] = v;
    }
    if (blockIdx.x == 0 && threadIdx.x < LP_) {
      b_inrs[threadIdx.x]  = (threadIdx.x < L_) ? irb[threadIdx.x] : 0.f;
      b_outrs[threadIdx.x] = (threadIdx.x < L_) ? orb[threadIdx.x] : 0.f;
    }
    return;
  }
  Cvt2 D = p.d[blockIdx.y];
  int n = D.Rp * D.Cp;
  if (D.C == D.Cp) {
    int nsrc = D.R * D.C;
    for (int i4 = (blockIdx.x * 256 + threadIdx.x) * 4; i4 < n; i4 += gridDim.x * 256 * 4) {
      __hip_bfloat16 o[4];
      if (i4 + 3 < nsrc) {
        f32x4 v = *(const f32x4*)(D.src + i4);
        #pragma unroll
        for (int q = 0; q < 4; ++q) o[q] = __float2bfloat16(v[q]);
      } else {
        #pragma unroll
        for (int q = 0; q < 4; ++q) { int i = i4 + q; o[q] = __float2bfloat16(i < nsrc ? D.src[i] : 0.f); }
      }
      *(u16x4*)(D.dst + i4) = *(u16x4*)o;
    }
  } else {
    for (int i = blockIdx.x * 256 + threadIdx.x; i < n; i += gridDim.x * 256) {
      int r = i / D.Cp, c = i - r * D.Cp;
      float v = (r < D.R && c < D.C) ? D.src[(size_t)r * D.C + c] : 0.f;
      D.dst[i] = __float2bfloat16(v);
    }
  }
}

// ---------------------------------------------------------------------------
// MFMA GEMM 128x128 (4 waves x 64x64). EPI: 0 none | 1 +bias | 2 (+bias)*aux |
// 3 softplus | 4 (+bias)*aux[(m%190)*N+n]
template<int EPI, bool OF32, bool OBF>
__global__ __launch_bounds__(256) void gemm128(
    const __hip_bfloat16* __restrict__ A, int lda, int M,
    const __hip_bfloat16* __restrict__ Bw, int Brows,
    const float* __restrict__ bias, const float* __restrict__ aux,
    float* __restrict__ Cf, __hip_bfloat16* __restrict__ Cb,
    int N, int K)
{
  __shared__ bf16x8 SA[2][512];
  __shared__ bf16x8 SB[2][512];
  const int tid = threadIdx.x;
  const int wave = tid >> 6, lane = tid & 63;
  const int m0 = blockIdx.y * 128, n0 = blockIdx.x * 128;
  const int wm = (wave >> 1) * 64, wn = (wave & 1) * 64;
  const int l15 = lane & 15, lkb = lane >> 4;

  f32x4 acc[4][4] = {};

  auto stage = [&](int bsel, int k0) {
    #pragma unroll
    for (int it = 0; it < 2; ++it) {
      int c = it * 256 + tid;
      int row = c & 127, kb = c >> 7;
      int ar = m0 + row; ar = ar < M ? ar : M - 1;
      const __hip_bfloat16* ga = A + (size_t)ar * lda + (k0 + kb * 8);
      LOAD_LDS16(ga, &SA[bsel][it * 256 + wave * 64]);
      int br = n0 + row; br = br < Brows ? br : Brows - 1;
      const __hip_bfloat16* gb = Bw + (size_t)br * K + (k0 + kb * 8);
      LOAD_LDS16(gb, &SB[bsel][it * 256 + wave * 64]);
    }
  };

  const int nk = K >> 5;
  stage(0, 0);
  __syncthreads();
  int buf = 0;
  for (int kt = 0; kt < nk; ++kt) {
    if (kt + 1 < nk) stage(buf ^ 1, (kt + 1) * 32);
    bf16x8 af[4], bq[4];
    #pragma unroll
    for (int f = 0; f < 4; ++f) {
      af[f] = SA[buf][lkb * 128 + wm + f * 16 + l15];
      bq[f] = SB[buf][lkb * 128 + wn + f * 16 + l15];
    }
    #pragma unroll
    for (int i = 0; i < 4; ++i)
      #pragma unroll
      for (int j = 0; j < 4; ++j)
        acc[i][j] = __builtin_amdgcn_mfma_f32_16x16x32_bf16(af[i], bq[j], acc[i][j], 0, 0, 0);
    __syncthreads();
    buf ^= 1;
  }

  #pragma unroll
  for (int i = 0; i < 4; ++i) {
    int r0 = m0 + wm + i * 16 + (lkb << 2);
    #pragma unroll
    for (int j = 0; j < 4; ++j) {
      int col = n0 + wn + j * 16 + l15;
      if (col >= N) continue;
      #pragma unroll
      for (int r = 0; r < 4; ++r) {
        int row = r0 + r;
        if (row >= M) continue;
        float v = acc[i][j][r];
        if (EPI >= 1) v += bias[col];
        if (EPI == 2) v *= aux[(size_t)row * N + col];
        if (EPI == 3) v = softplusf(v);
        if (EPI == 4) v *= aux[(size_t)(row % L_) * N + col];
        if (OF32) Cf[(size_t)row * N + col] = v;
        if (OBF)  Cb[(size_t)row * N + col] = __float2bfloat16(v);
      }
    }
  }
}

// ---------------------------------------------------------------------------
// MFMA GEMM 64x64 (4 waves x 32x32) — for small-N / latency-bound links.
template<int EPI, bool OF32, bool OBF>
__global__ __launch_bounds__(256) void gemm64(
    const __hip_bfloat16* __restrict__ A, int lda, int M,
    const __hip_bfloat16* __restrict__ Bw, int Brows,
    const float* __restrict__ bias, const float* __restrict__ aux,
    float* __restrict__ Cf, __hip_bfloat16* __restrict__ Cb,
    int N, int K)
{
  __shared__ bf16x8 SA[2][256];
  __shared__ bf16x8 SB[2][256];
  const int tid = threadIdx.x;
  const int wave = tid >> 6, lane = tid & 63;
  const int m0 = blockIdx.y * 64, n0 = blockIdx.x * 64;
  const int wm = (wave >> 1) * 32, wn = (wave & 1) * 32;
  const int l15 = lane & 15, lkb = lane >> 4;

  f32x4 acc[2][2] = {};

  auto stage = [&](int bsel, int k0) {
    int row = tid & 63, kb = tid >> 6;
    int ar = m0 + row; ar = ar < M ? ar : M - 1;
    const __hip_bfloat16* ga = A + (size_t)ar * lda + (k0 + kb * 8);
    LOAD_LDS16(ga, &SA[bsel][wave * 64]);
    int br = n0 + row; br = br < Brows ? br : Brows - 1;
    const __hip_bfloat16* gb = Bw + (size_t)br * K + (k0 + kb * 8);
    LOAD_LDS16(gb, &SB[bsel][wave * 64]);
  };

  const int nk = K >> 5;
  stage(0, 0);
  __syncthreads();
  int buf = 0;
  for (int kt = 0; kt < nk; ++kt) {
    if (kt + 1 < nk) stage(buf ^ 1, (kt + 1) * 32);
    bf16x8 af[2], bq[2];
    #pragma unroll
    for (int f = 0; f < 2; ++f) {
      af[f] = SA[buf][lkb * 64 + wm + f * 16 + l15];
      bq[f] = SB[buf][lkb * 64 + wn + f * 16 + l15];
    }
    #pragma unroll
    for (int i = 0; i < 2; ++i)
      #pragma unroll
      for (int j = 0; j < 2; ++j)
        acc[i][j] = __builtin_amdgcn_mfma_f32_16x16x32_bf16(af[i], bq[j], acc[i][j], 0, 0, 0);
    __syncthreads();
    buf ^= 1;
  }

  #pragma unroll
  for (int i = 0; i < 2; ++i) {
    int r0 = m0 + wm + i * 16 + (lkb << 2);
    #pragma unroll
    for (int j = 0; j < 2; ++j) {
      int col = n0 + wn + j * 16 + l15;
      if (col >= N) continue;
      #pragma unroll
      for (int r = 0; r < 4; ++r) {
        int row = r0 + r;
        if (row >= M) continue;
        float v = acc[i][j][r];
        if (EPI >= 1) v += bias[col];
        if (EPI == 2) v *= aux[(size_t)row * N + col];
        if (EPI == 3) v = softplusf(v);
        if (EPI == 4) v *= aux[(size_t)(row % L_) * N + col];
        if (OF32) Cf[(size_t)row * N + col] = v;
        if (OBF)  Cb[(size_t)row * N + col] = __float2bfloat16(v);
      }
    }
  }
}

// ---------------------------------------------------------------------------
// out_proj GEMM with fused A-operand: A[m][k] = (y_f+y_b)*silu(z) on the fly.
__global__ __launch_bounds__(256) void gemm64_yz(
    const __hip_bfloat16* __restrict__ Y,   // [2][LB_][DI_] bf16 (y_f, y_b)
    const __hip_bfloat16* __restrict__ Xz,  // [LB_][2*DI_]  bf16 (z at +DI_)
    const __hip_bfloat16* __restrict__ Bw,  // [512][1024]
    __hip_bfloat16* __restrict__ Cb,        // [LB_][512]
    int M, int N, int K)
{
  __shared__ bf16x8 SA[2][256];
  __shared__ bf16x8 SB[2][256];
  const int tid = threadIdx.x;
  const int wave = tid >> 6, lane = tid & 63;
  const int m0 = blockIdx.y * 64, n0 = blockIdx.x * 64;
  const int wm = (wave >> 1) * 32, wn = (wave & 1) * 32;
  const int l15 = lane & 15, lkb = lane >> 4;

  f32x4 acc[2][2] = {};

  auto stage = [&](int bsel, int k0) {
    int row = tid & 63, kb = tid >> 6;
    int ar = m0 + row; ar = ar < M ? ar : M - 1;
    size_t o = (size_t)ar * DI_ + (k0 + kb * 8);
    u16x4 f0 = *(const u16x4*)(Y + o);
    u16x4 f1 = *(const u16x4*)(Y + o + 4);
    u16x4 g0 = *(const u16x4*)(Y + LBDI_ + o);
    u16x4 g1 = *(const u16x4*)(Y + LBDI_ + o + 4);
    size_t zo = (size_t)ar * (2 * DI_) + DI_ + (k0 + kb * 8);
    u16x4 z0 = *(const u16x4*)(Xz + zo);
    u16x4 z1 = *(const u16x4*)(Xz + zo + 4);
    unsigned short av[8];
    #pragma unroll
    for (int q = 0; q < 4; ++q) {
      float v = (bf2f(f0[q]) + bf2f(g0[q])) * siluf(bf2f(z0[q]));
      av[q] = __bfloat16_as_ushort(__float2bfloat16(v));
      float w = (bf2f(f1[q]) + bf2f(g1[q])) * siluf(bf2f(z1[q]));
      av[q + 4] = __bfloat16_as_ushort(__float2bfloat16(w));
    }
    SA[bsel][wave * 64 + row] = *(bf16x8*)av;
    int br = n0 + row; br = br < N ? br : N - 1;
    const __hip_bfloat16* gb = Bw + (size_t)br * K + (k0 + kb * 8);
    LOAD_LDS16(gb, &SB[bsel][wave * 64]);
  };

  const int nk = K >> 5;
  stage(0, 0);
  __syncthreads();
  int buf = 0;
  for (int kt = 0; kt < nk; ++kt) {
    if (kt + 1 < nk) stage(buf ^ 1, (kt + 1) * 32);
    bf16x8 af[2], bq[2];
    #pragma unroll
    for (int f = 0; f < 2; ++f) {
      af[f] = SA[buf][lkb * 64 + wm + f * 16 + l15];
      bq[f] = SB[buf][lkb * 64 + wn + f * 16 + l15];
    }
    #pragma unroll
    for (int i = 0; i < 2; ++i)
      #pragma unroll
      for (int j = 0; j < 2; ++j)
        acc[i][j] = __builtin_amdgcn_mfma_f32_16x16x32_bf16(af[i], bq[j], acc[i][j], 0, 0, 0);
    __syncthreads();
    buf ^= 1;
  }

  #pragma unroll
  for (int i = 0; i < 2; ++i) {
    int r0 = m0 + wm + i * 16 + (lkb << 2);
    #pragma unroll
    for (int j = 0; j < 2; ++j) {
      int col = n0 + wn + j * 16 + l15;
      if (col >= N) continue;
      #pragma unroll
      for (int r = 0; r < 4; ++r) {
        int row = r0 + r;
        if (row >= M) continue;
        Cb[(size_t)row * N + col] = __float2bfloat16(acc[i][j][r]);
      }
    }
  }
}

// ---------------------------------------------------------------------------
// Depthwise conv(k=4) + bias + silu, both directions; 4 channels per thread.
__global__ __launch_bounds__(256) void conv_silu(
    const __hip_bfloat16* __restrict__ xz, const float* __restrict__ w,
    const float* __restrict__ cb, __hip_bfloat16* __restrict__ xcbf)
{
  int t = blockIdx.x * 256 + threadIdx.x;
  int c4 = (t & (DI_ / 4 - 1)) * 4;
  int bl = t >> 8;
  int l = bl % L_;
  int b = bl / L_;
  const __hip_bfloat16* base = xz + (size_t)b * L_ * (2 * DI_) + c4;
  float xr[7][4];
  #pragma unroll
  for (int j = 0; j < 7; ++j) {
    int gl = l + j - 3;
    if (gl >= 0 && gl < L_) {
      u16x4 v = *(const u16x4*)(base + (size_t)gl * (2 * DI_));
      #pragma unroll
      for (int q = 0; q < 4; ++q) xr[j][q] = bf2f(v[q]);
    } else {
      #pragma unroll
      for (int q = 0; q < 4; ++q) xr[j][q] = 0.f;
    }
  }
  __hip_bfloat16 of[4], ob[4];
  #pragma unroll
  for (int q = 0; q < 4; ++q) {
    int c = c4 + q;
    float w0 = w[c * 4], w1 = w[c * 4 + 1], w2 = w[c * 4 + 2], w3 = w[c * 4 + 3];
    float bias = cb[c];
    float sf = fmaf(w0, xr[0][q], fmaf(w1, xr[1][q], fmaf(w2, xr[2][q], fmaf(w3, xr[3][q], bias))));
    float sb = fmaf(w0, xr[6][q], fmaf(w1, xr[5][q], fmaf(w2, xr[4][q], fmaf(w3, xr[3][q], bias))));
    of[q] = __float2bfloat16(siluf(sf));
    ob[q] = __float2bfloat16(siluf(sb));
  }
  size_t o = (size_t)bl * DI_ + c4;
  *(u16x4*)(xcbf + o)         = *(u16x4*)of;
  *(u16x4*)(xcbf + LBDI_ + o) = *(u16x4*)ob;
}

// ---------------------------------------------------------------------------
// Selective scan v9 (proven 57.5 us, VGPR 48): 32 d x 8 chunks of 24; B/C
// straight from global (wave-broadcast); log-depth exp powers; runtime-bound
// loops (NO per-step register caches -> no spill).
#define SCT_ 24
#define HS_  17        // padded state stride for sH
__global__ __launch_bounds__(256) void scan_v9(
    const __hip_bfloat16* __restrict__ dtb, // [RT_][DI_] bf16
    const float* __restrict__ xd,           // [RT_][64]  f32
    const __hip_bfloat16* __restrict__ xc,  // [RT_][DI_] bf16
    const float* __restrict__ A_log, const float* __restrict__ Dv,
    __hip_bfloat16* __restrict__ y)         // [RT_][DI_] bf16
{
  __shared__ float sH[256 * HS_];    // 17408 B
  __shared__ float sS[256];          //  1024 B

  const int tid   = threadIdx.x;
  const int dl    = tid & 31;
  const int chunk = tid >> 5;
  const int dglob = blockIdx.x * 32 + dl;
  const int b     = blockIdx.y;
  const int dir   = blockIdx.z;
  const int rowbase = dir * LB_ + b * L_;
  const unsigned short* xcu = (const unsigned short*)xc;
  const unsigned short* dtu = (const unsigned short*)dtb;
  const float* Arow = A_log + dglob * 16;

  const float A0 = -__expf(Arow[0]);
  bool fast = true;
  #pragma unroll
  for (int s = 1; s < 16; ++s) {
    float As = -__expf(Arow[s]);
    fast = fast && (fabsf(As - (float)(s + 1) * A0) <= 1e-4f * (float)(s + 1));
  }
  const float Dd = Dv[dglob];

  const int cstart = chunk * SCT_;
  const int clen = (cstart + SCT_ <= L_) ? SCT_ : (L_ > cstart ? L_ - cstart : 0);

  auto powers = [&](float e1, float* ep) {
    ep[0] = e1;
    #pragma unroll
    for (int s = 1; s < 16; ++s) ep[s] = ep[(s - 1) >> 1] * ep[s >> 1];
  };

  // ---- pass 1: local scan from 0 ----
  float h[16];
  #pragma unroll
  for (int s = 0; s < 16; ++s) h[s] = 0.f;
  float dsum = 0.f;
  for (int k = 0; k < clen; ++k) {
    int l   = cstart + k;
    int pos = dir ? (L_ - 1 - l) : l;
    size_t grow = (size_t)(rowbase + pos);
    float dtv = bf2f(dtu[grow * DI_ + dglob]);
    float xcv = bf2f(xcu[grow * DI_ + dglob]);
    float du  = dtv * xcv;
    dsum += dtv;
    const float* brow = xd + grow * 64;
    f32x4 bq0 = *(const f32x4*)(brow + 32);
    f32x4 bq1 = *(const f32x4*)(brow + 36);
    f32x4 bq2 = *(const f32x4*)(brow + 40);
    f32x4 bq3 = *(const f32x4*)(brow + 44);
    float ep[16];
    if (fast) {
      powers(__expf(dtv * A0), ep);
    } else {
      #pragma unroll
      for (int s = 0; s < 16; ++s) ep[s] = __expf(dtv * -__expf(Arow[s]));
    }
    #pragma unroll
    for (int s = 0; s < 16; ++s) {
      float Bv = (s < 4) ? bq0[s & 3] : (s < 8) ? bq1[s & 3] : (s < 12) ? bq2[s & 3] : bq3[s & 3];
      h[s] = fmaf(ep[s], h[s], du * Bv);
    }
  }
  {
    float* hr = sH + tid * HS_;
    #pragma unroll
    for (int s = 0; s < 16; ++s) hr[s] = h[s];
    sS[tid] = dsum;
  }
  __syncthreads();

  // ---- combine: h_in = fold over previous chunks ----
  float hin[16];
  #pragma unroll
  for (int s = 0; s < 16; ++s) hin[s] = 0.f;
  for (int c = 0; c < chunk; ++c) {
    float S = sS[c * 32 + dl];
    const float* hp = sH + (c * 32 + dl) * HS_;
    float ep[16];
    if (fast) {
      powers(__expf(A0 * S), ep);
    } else {
      #pragma unroll
      for (int s = 0; s < 16; ++s) ep[s] = __expf(-__expf(Arow[s]) * S);
    }
    #pragma unroll
    for (int s = 0; s < 16; ++s)
      hin[s] = fmaf(ep[s], hin[s], hp[s]);
  }

  // ---- pass 2: scan with h_in, emit y ----
  #pragma unroll
  for (int s = 0; s < 16; ++s) h[s] = hin[s];
  for (int k = 0; k < clen; ++k) {
    int l   = cstart + k;
    int pos = dir ? (L_ - 1 - l) : l;
    size_t grow = (size_t)(rowbase + pos);
    float dtv = bf2f(dtu[grow * DI_ + dglob]);
    float xcv = bf2f(xcu[grow * DI_ + dglob]);
    float du  = dtv * xcv;
    const float* brow = xd + grow * 64;
    f32x4 bq0 = *(const f32x4*)(brow + 32);
    f32x4 bq1 = *(const f32x4*)(brow + 36);
    f32x4 bq2 = *(const f32x4*)(brow + 40);
    f32x4 bq3 = *(const f32x4*)(brow + 44);
    f32x4 cq0 = *(const f32x4*)(brow + 48);
    f32x4 cq1 = *(const f32x4*)(brow + 52);
    f32x4 cq2 = *(const f32x4*)(brow + 56);
    f32x4 cq3 = *(const f32x4*)(brow + 60);
    float ep[16];
    if (fast) {
      powers(__expf(dtv * A0), ep);
    } else {
      #pragma unroll
      for (int s = 0; s < 16; ++s) ep[s] = __expf(dtv * -__expf(Arow[s]));
    }
    float acc = 0.f;
    #pragma unroll
    for (int s = 0; s < 16; ++s) {
      float Bv = (s < 4) ? bq0[s & 3] : (s < 8) ? bq1[s & 3] : (s < 12) ? bq2[s & 3] : bq3[s & 3];
      float Cv = (s < 4) ? cq0[s & 3] : (s < 8) ? cq1[s & 3] : (s < 12) ? cq2[s & 3] : cq3[s & 3];
      h[s] = fmaf(ep[s], h[s], du * Bv);
      acc  = fmaf(h[s], Cv, acc);
    }
    y[grow * DI_ + dglob] = __float2bfloat16(fmaf(xcv, Dd, acc));
  }
}

// ---------------------------------------------------------------------------
// tanh-LayerNorm over (L, D) per batch.
__global__ __launch_bounds__(256) void ln_partial(const float* __restrict__ x,
                                                  float* __restrict__ partials)
{
  int b = blockIdx.y, ch = blockIdx.x;
  const float* xb = x + (size_t)b * (L_ * DM_);
  int lo = ch * 12160, hi = lo + 12160;
  float s = 0.f, s2 = 0.f;
  for (int i = lo + threadIdx.x; i < hi; i += 256) {
    float t = tanhf(xb[i]);
    s += t; s2 = fmaf(t, t, s2);
  }
  #pragma unroll
  for (int off = 32; off > 0; off >>= 1) { s += __shfl_down(s, off); s2 += __shfl_down(s2, off); }
  __shared__ float rs[4], rs2[4];
  int wid = threadIdx.x >> 6, lane = threadIdx.x & 63;
  if (lane == 0) { rs[wid] = s; rs2[wid] = s2; }
  __syncthreads();
  if (threadIdx.x == 0) {
    partials[(b * 8 + ch) * 2 + 0] = rs[0] + rs[1] + rs[2] + rs[3];
    partials[(b * 8 + ch) * 2 + 1] = rs2[0] + rs2[1] + rs2[2] + rs2[3];
  }
}

__global__ __launch_bounds__(256) void ln_final(const float* __restrict__ x,
    const float* __restrict__ partials,
    const float* __restrict__ nw, const float* __restrict__ nb,
    float* __restrict__ out)
{
  int b = blockIdx.y, ch = blockIdx.x;
  float S = 0.f, S2 = 0.f;
  #pragma unroll
  for (int i = 0; i < 8; ++i) { S += partials[(b * 8 + i) * 2 + 0]; S2 += partials[(b * 8 + i) * 2 + 1]; }
  const float inv = 1.f / (float)(L_ * DM_);
  float mu = S * inv;
  float var = S2 * inv - mu * mu;
  float r = rsqrtf(var + 1e-5f);
  const float* xb = x + (size_t)b * (L_ * DM_);
  float* ob = out + (size_t)b * (L_ * DM_);
  int lo = ch * 12160, hi = lo + 12160;
  for (int i = lo + threadIdx.x; i < hi; i += 256) {
    float t = tanhf(xb[i]);
    ob[i] = fmaf((t - mu) * r, nw[i], nb[i]);
  }
}

// ---------------------------------------------------------------------------
extern "C" void kernel_launch(void* const* d_in, const int* in_sizes, int n_in,
                              void* d_out, int out_size, void* d_ws, size_t ws_size,
                              hipStream_t stream)
{
  const float* x            = (const float*)d_in[0];
  const void*  pc_mask      = d_in[1];
  const float* in_resize_w  = (const float*)d_in[2];
  const float* in_resize_b  = (const float*)d_in[3];
  const float* in_reset_w   = (const float*)d_in[4];
  const float* in_reset_b   = (const float*)d_in[5];
  const float* out_resize_w = (const float*)d_in[6];
  const float* out_resize_b = (const float*)d_in[7];
  const float* out_reset_w  = (const float*)d_in[8];
  const float* out_reset_b  = (const float*)d_in[9];
  const float* in_proj_w    = (const float*)d_in[10];
  const float* conv_w       = (const float*)d_in[11];
  const float* conv_b       = (const float*)d_in[12];
  const float* x_proj_w     = (const float*)d_in[13];
  const float* dt_proj_w    = (const float*)d_in[14];
  const float* dt_proj_b    = (const float*)d_in[15];
  const float* A_log        = (const float*)d_in[16];
  const float* Dv           = (const float*)d_in[17];
  const float* out_proj_w   = (const float*)d_in[18];
  const float* norm_w       = (const float*)d_in[19];
  const float* norm_b       = (const float*)d_in[20];

  // ---- workspace layout ----
  float* W = (float*)d_ws;
  float* maskf    = W + 0;         // 190*192 = 36480
  float* b_inrs   = W + 36480;     // 192
  float* b_outrs  = W + 36672;     // 192
  float* xd       = W + 36864;     // 6080*64 = 389120 (row-major f32)
  float* partials = W + 425984;    // 256
  __hip_bfloat16* BF = (__hip_bfloat16*)(W + 426240);
  __hip_bfloat16* w_inrs  = BF + 0;         // 192*512
  __hip_bfloat16* w_inrt  = BF + 98304;     // 512*192
  __hip_bfloat16* w_inpj  = BF + 196608;    // 2048*512
  __hip_bfloat16* w_xpj   = BF + 1245184;   // 64*1024
  __hip_bfloat16* w_dtpj  = BF + 1310720;   // 1024*32
  __hip_bfloat16* w_outpj = BF + 1343488;   // 512*1024
  __hip_bfloat16* w_outrs = BF + 1867776;   // 192*512
  __hip_bfloat16* w_outrt = BF + 1966080;   // 512*192
  __hip_bfloat16* x_bf    = BF + 2064384;   // 3040*512
  __hip_bfloat16* h1_bf   = BF + 3620864;   // 3040*192
  __hip_bfloat16* h_bf    = BF + 4204544;   // 3040*512
  __hip_bfloat16* xz_bf   = BF + 5761024;   // 3040*2048
  __hip_bfloat16* xc_bf   = BF + 11986944;  // 2*3040*1024
  __hip_bfloat16* y_bf    = BF + 18212864;  // 6080*1024
  __hip_bfloat16* xd_bf   = BF + 24438784;  // 6080*64
  __hip_bfloat16* dt_bf   = BF + 24827904;  // 6080*1024
  __hip_bfloat16* o_pre   = BF + 31053824;  // 3040*512
  __hip_bfloat16* o2_bf   = BF + 32610304;  // 3040*192

  float* out_ln = (float*)d_out;
  float* out_o  = (float*)d_out + (size_t)LB_ * DM_;

  dim3 blk(256);

  CvtPack2 P;
  P.d[0] = Cvt2{ x,            x_bf,    3040, 512, 3040, 512 };
  P.d[1] = Cvt2{ in_resize_w,  w_inrs,  190, 512, 192, 512 };
  P.d[2] = Cvt2{ in_reset_w,   w_inrt,  512, 190, 512, 192 };
  P.d[3] = Cvt2{ in_proj_w,    w_inpj,  2048, 512, 2048, 512 };
  P.d[4] = Cvt2{ x_proj_w,     w_xpj,   64, 1024, 64, 1024 };
  P.d[5] = Cvt2{ dt_proj_w,    w_dtpj,  1024, 32, 1024, 32 };
  P.d[6] = Cvt2{ out_proj_w,   w_outpj, 512, 1024, 512, 1024 };
  P.d[7] = Cvt2{ out_resize_w, w_outrs, 190, 512, 192, 512 };
  P.d[8] = Cvt2{ out_reset_w,  w_outrt, 512, 190, 512, 192 };
  cvt_all3<<<dim3(256, 10), blk, 0, stream>>>(P, pc_mask, maskf,
      in_resize_b, out_resize_b, b_inrs, b_outrs);

  // h1 = x @ in_resize_w^T + b                       (m[0,0]==1: diag of eye)
  gemm64<1,false,true><<<dim3(3,48), blk, 0, stream>>>(x_bf, 512, 3040, w_inrs, 192, b_inrs, nullptr, nullptr, h1_bf, LP_, 512);
  // h = (h1 @ in_reset_w^T + b) * x
  gemm64<2,false,true><<<dim3(8,48), blk, 0, stream>>>(h1_bf, LP_, 3040, w_inrt, 512, in_reset_b, x, nullptr, h_bf, 512, LP_);
  // xz = h @ in_proj_w^T
  gemm128<0,false,true><<<dim3(16,24), blk, 0, stream>>>(h_bf, 512, 3040, w_inpj, 2048, nullptr, nullptr, nullptr, xz_bf, 2048, 512);
  // conv + silu (both dirs)
  conv_silu<<<dim3(LBDI_/1024), blk, 0, stream>>>(xz_bf, conv_w, conv_b, xc_bf);
  // x_dbl = xc @ x_proj_w^T  (both dirs, M=6080); f32 + bf16 row-major
  gemm64<0,true,true><<<dim3(1,95), blk, 0, stream>>>(xc_bf, 1024, 6080, w_xpj, 64, nullptr, nullptr, xd, xd_bf, 64, 1024);
  // dt = softplus(x_dbl[:,:32] @ dt_proj_w^T + b) -> bf16
  gemm64<3,false,true><<<dim3(16,95), blk, 0, stream>>>(xd_bf, 64, 6080, w_dtpj, 1024, dt_proj_b, nullptr, nullptr, dt_bf, 1024, 32);
  // selective scan (v9: proven fast, no spill)
  scan_v9<<<dim3(32, 16, 2), blk, 0, stream>>>(dt_bf, xd, xc_bf, A_log, Dv, y_bf);
  // o_pre = ((y_f+y_b)*silu(z)) @ out_proj_w^T   (fused combine)
  gemm64_yz<<<dim3(8,48), blk, 0, stream>>>(y_bf, xz_bf, w_outpj, o_pre, 3040, 512, 1024);
  // o2 = (o_pre @ out_resize_w^T + b) * mask[l,:]
  gemm64<4,false,true><<<dim3(3,48), blk, 0, stream>>>(o_pre, 512, 3040, w_outrs, 192, b_outrs, maskf, nullptr, o2_bf, LP_, 512);
  // o = (o2 @ out_reset_w^T + b) * x  -> output 1
  gemm64<2,true,false><<<dim3(8,48), blk, 0, stream>>>(o2_bf, LP_, 3040, w_outrt, 512, out_reset_b, x, out_o, nullptr, 512, LP_);
  // output 0: layernorm(tanh(x))
  dim3 lgrid(8, B_);
  ln_partial<<<lgrid, blk, 0, stream>>>(x, partials);
  ln_final<<<lgrid, blk, 0, stream>>>(x, partials, norm_w, norm_b, out_ln);
}

// Round 13
// 272.448 us; speedup vs baseline: 2.1216x; 1.0062x over previous
//
#include <hip/hip_runtime.h>
#include <hip/hip_bf16.h>

#define B_    16
#define L_    190
#define LP_   192        // padded L
#define DM_   512
#define DI_   1024
#define LB_   3040       // B_*L_
#define RT_   6080       // 2*LB_ rows (dir-major)
#define LBDI_ 3112960    // LB_*DI_

typedef __attribute__((ext_vector_type(8))) short bf16x8;
typedef __attribute__((ext_vector_type(4))) float f32x4;
typedef __attribute__((ext_vector_type(4))) unsigned short u16x4;
typedef __attribute__((ext_vector_type(8))) unsigned short u16x8;

typedef const __attribute__((address_space(1))) void gvoid;
typedef __attribute__((address_space(3))) void lvoid;
#define LOAD_LDS16(g, l) __builtin_amdgcn_global_load_lds((gvoid*)(g), (lvoid*)(l), 16, 0, 0)

__device__ __forceinline__ float siluf(float v) { return v / (1.f + __expf(-v)); }
__device__ __forceinline__ float softplusf(float v) {
  return v > 0.f ? v + log1pf(__expf(-v)) : log1pf(__expf(v));
}
__device__ __forceinline__ float bf2f(unsigned short u) {
  unsigned int w = (unsigned int)u << 16; return __builtin_bit_cast(float, w);
}

// ---------------------------------------------------------------------------
// Segments 0-7: f32 -> padded bf16 (seg 7 transposed). y==8: mask + b_outrs.
// y==9: bias_comb = in_reset_w @ in_resize_b + in_reset_b. y==10: ln_partial.
struct Cvt2 { const float* src; __hip_bfloat16* dst; int R, C, Rp, Cp, T; };
struct CvtPack2 { Cvt2 d[8]; };

__global__ __launch_bounds__(256) void cvt_all4(CvtPack2 p,
    const void* __restrict__ pcm, float* __restrict__ maskf,
    const float* __restrict__ irb, const float* __restrict__ orb,
    float* __restrict__ b_outrs,
    const float* __restrict__ irw, const float* __restrict__ irtb,
    float* __restrict__ b_comb,
    const float* __restrict__ x, float* __restrict__ partials)
{
  if (blockIdx.y == 8) {
    __shared__ int votes[3];
    if (threadIdx.x < 3) votes[threadIdx.x] = 0;
    __syncthreads();
    if (threadIdx.x < 48) {
      int idx = threadIdx.x * 191;
      const unsigned char* p8  = (const unsigned char*)pcm;
      const unsigned int*  p32 = (const unsigned int*)pcm;
      if (p8[idx] == 1) atomicAdd(&votes[0], 1);
      unsigned int v = p32[idx];
      if (v == 1u)          atomicAdd(&votes[1], 1);
      if (v == 0x3f800000u) atomicAdd(&votes[2], 1);
    }
    __syncthreads();
    int mode = (votes[0] >= 48) ? 0 : (votes[1] >= 48 ? 1 : (votes[2] >= 48 ? 2 : 0));
    for (int i = blockIdx.x * 256 + threadIdx.x; i < L_ * LP_; i += gridDim.x * 256) {
      int r = i / LP_, c = i % LP_;
      float v = 0.f;
      if (c < L_) {
        int s = r * L_ + c;
        if (mode == 0)      v = ((const unsigned char*)pcm)[s] ? 1.f : 0.f;
        else if (mode == 1) v = ((const int*)pcm)[s] ? 1.f : 0.f;
        else                v = ((const float*)pcm)[s];
      }
      maskf[i] = v;
    }
    if (blockIdx.x == 0 && threadIdx.x < LP_)
      b_outrs[threadIdx.x] = (threadIdx.x < L_) ? orb[threadIdx.x] : 0.f;
    return;
  }
  if (blockIdx.y == 9) {
    if (blockIdx.x < 2) {
      int n = blockIdx.x * 256 + threadIdx.x;   // < 512
      const float* wrow = irw + (size_t)n * L_;
      float s = 0.f;
      for (int k = 0; k < L_; ++k) s = fmaf(wrow[k], irb[k], s);
      b_comb[n] = s + irtb[n];
    }
    return;
  }
  if (blockIdx.y == 10) {
    if (blockIdx.x < 128) {
      int bb = blockIdx.x >> 3, ch = blockIdx.x & 7;
      const float* xb = x + (size_t)bb * (L_ * DM_);
      int lo = ch * 12160, hi = lo + 12160;
      float s = 0.f, s2 = 0.f;
      for (int i = lo + threadIdx.x; i < hi; i += 256) {
        float t = tanhf(xb[i]);
        s += t; s2 = fmaf(t, t, s2);
      }
      #pragma unroll
      for (int off = 32; off > 0; off >>= 1) { s += __shfl_down(s, off); s2 += __shfl_down(s2, off); }
      __shared__ float rs[4], rs2[4];
      int wid = threadIdx.x >> 6, lane = threadIdx.x & 63;
      if (lane == 0) { rs[wid] = s; rs2[wid] = s2; }
      __syncthreads();
      if (threadIdx.x == 0) {
        partials[(bb * 8 + ch) * 2 + 0] = rs[0] + rs[1] + rs[2] + rs[3];
        partials[(bb * 8 + ch) * 2 + 1] = rs2[0] + rs2[1] + rs2[2] + rs2[3];
      }
    }
    return;
  }
  Cvt2 D = p.d[blockIdx.y];
  int n = D.Rp * D.Cp;
  if (D.T) {
    // dst[r][c] = src[c][r], src is [C][R]
    for (int i = blockIdx.x * 256 + threadIdx.x; i < n; i += gridDim.x * 256) {
      int r = i / D.Cp, c = i - r * D.Cp;
      float v = (c < D.C && r < D.R) ? D.src[(size_t)c * D.R + r] : 0.f;
      D.dst[i] = __float2bfloat16(v);
    }
  } else if (D.C == D.Cp) {
    int nsrc = D.R * D.C;
    for (int i4 = (blockIdx.x * 256 + threadIdx.x) * 4; i4 < n; i4 += gridDim.x * 256 * 4) {
      __hip_bfloat16 o[4];
      if (i4 + 3 < nsrc) {
        f32x4 v = *(const f32x4*)(D.src + i4);
        #pragma unroll
        for (int q = 0; q < 4; ++q) o[q] = __float2bfloat16(v[q]);
      } else {
        #pragma unroll
        for (int q = 0; q < 4; ++q) { int i = i4 + q; o[q] = __float2bfloat16(i < nsrc ? D.src[i] : 0.f); }
      }
      *(u16x4*)(D.dst + i4) = *(u16x4*)o;
    }
  } else {
    for (int i = blockIdx.x * 256 + threadIdx.x; i < n; i += gridDim.x * 256) {
      int r = i / D.Cp, c = i - r * D.Cp;
      float v = (r < D.R && c < D.C) ? D.src[(size_t)r * D.C + c] : 0.f;
      D.dst[i] = __float2bfloat16(v);
    }
  }
}

// ---------------------------------------------------------------------------
// MFMA GEMM 128x128 (4 waves x 64x64). EPI: 0 none | 1 +bias | 2 (+bias)*aux |
// 3 softplus | 4 (+bias)*aux[(m%190)*N+n]
template<int EPI, bool OF32, bool OBF>
__global__ __launch_bounds__(256) void gemm128(
    const __hip_bfloat16* __restrict__ A, int lda, int M,
    const __hip_bfloat16* __restrict__ Bw, int Brows,
    const float* __restrict__ bias, const float* __restrict__ aux,
    float* __restrict__ Cf, __hip_bfloat16* __restrict__ Cb,
    int N, int K)
{
  __shared__ bf16x8 SA[2][512];
  __shared__ bf16x8 SB[2][512];
  const int tid = threadIdx.x;
  const int wave = tid >> 6, lane = tid & 63;
  const int m0 = blockIdx.y * 128, n0 = blockIdx.x * 128;
  const int wm = (wave >> 1) * 64, wn = (wave & 1) * 64;
  const int l15 = lane & 15, lkb = lane >> 4;

  f32x4 acc[4][4] = {};

  auto stage = [&](int bsel, int k0) {
    #pragma unroll
    for (int it = 0; it < 2; ++it) {
      int c = it * 256 + tid;
      int row = c & 127, kb = c >> 7;
      int ar = m0 + row; ar = ar < M ? ar : M - 1;
      const __hip_bfloat16* ga = A + (size_t)ar * lda + (k0 + kb * 8);
      LOAD_LDS16(ga, &SA[bsel][it * 256 + wave * 64]);
      int br = n0 + row; br = br < Brows ? br : Brows - 1;
      const __hip_bfloat16* gb = Bw + (size_t)br * K + (k0 + kb * 8);
      LOAD_LDS16(gb, &SB[bsel][it * 256 + wave * 64]);
    }
  };

  const int nk = K >> 5;
  stage(0, 0);
  __syncthreads();
  int buf = 0;
  for (int kt = 0; kt < nk; ++kt) {
    if (kt + 1 < nk) stage(buf ^ 1, (kt + 1) * 32);
    bf16x8 af[4], bq[4];
    #pragma unroll
    for (int f = 0; f < 4; ++f) {
      af[f] = SA[buf][lkb * 128 + wm + f * 16 + l15];
      bq[f] = SB[buf][lkb * 128 + wn + f * 16 + l15];
    }
    #pragma unroll
    for (int i = 0; i < 4; ++i)
      #pragma unroll
      for (int j = 0; j < 4; ++j)
        acc[i][j] = __builtin_amdgcn_mfma_f32_16x16x32_bf16(af[i], bq[j], acc[i][j], 0, 0, 0);
    __syncthreads();
    buf ^= 1;
  }

  #pragma unroll
  for (int i = 0; i < 4; ++i) {
    int r0 = m0 + wm + i * 16 + (lkb << 2);
    #pragma unroll
    for (int j = 0; j < 4; ++j) {
      int col = n0 + wn + j * 16 + l15;
      if (col >= N) continue;
      #pragma unroll
      for (int r = 0; r < 4; ++r) {
        int row = r0 + r;
        if (row >= M) continue;
        float v = acc[i][j][r];
        if (EPI >= 1) v += bias[col];
        if (EPI == 2) v *= aux[(size_t)row * N + col];
        if (EPI == 3) v = softplusf(v);
        if (EPI == 4) v *= aux[(size_t)(row % L_) * N + col];
        if (OF32) Cf[(size_t)row * N + col] = v;
        if (OBF)  Cb[(size_t)row * N + col] = __float2bfloat16(v);
      }
    }
  }
}

// ---------------------------------------------------------------------------
// MFMA GEMM 64x64 (4 waves x 32x32). AF32: A is f32, reg-staged + converted.
template<int EPI, bool OF32, bool OBF, bool AF32>
__global__ __launch_bounds__(256) void gemm64(
    const __hip_bfloat16* __restrict__ A, int lda, int M,
    const __hip_bfloat16* __restrict__ Bw, int Brows,
    const float* __restrict__ bias, const float* __restrict__ aux,
    float* __restrict__ Cf, __hip_bfloat16* __restrict__ Cb,
    int N, int K)
{
  __shared__ bf16x8 SA[2][256];
  __shared__ bf16x8 SB[2][256];
  const int tid = threadIdx.x;
  const int wave = tid >> 6, lane = tid & 63;
  const int m0 = blockIdx.y * 64, n0 = blockIdx.x * 64;
  const int wm = (wave >> 1) * 32, wn = (wave & 1) * 32;
  const int l15 = lane & 15, lkb = lane >> 4;

  f32x4 acc[2][2] = {};

  auto stage = [&](int bsel, int k0) {
    int row = tid & 63, kb = tid >> 6;
    int ar = m0 + row; ar = ar < M ? ar : M - 1;
    if (AF32) {
      const float* ga = (const float*)A + (size_t)ar * lda + (k0 + kb * 8);
      f32x4 v0 = *(const f32x4*)ga;
      f32x4 v1 = *(const f32x4*)(ga + 4);
      __hip_bfloat16 o[8];
      #pragma unroll
      for (int q = 0; q < 4; ++q) { o[q] = __float2bfloat16(v0[q]); o[q + 4] = __float2bfloat16(v1[q]); }
      SA[bsel][wave * 64 + row] = *(bf16x8*)o;
    } else {
      const __hip_bfloat16* ga = A + (size_t)ar * lda + (k0 + kb * 8);
      LOAD_LDS16(ga, &SA[bsel][wave * 64]);
    }
    int br = n0 + row; br = br < Brows ? br : Brows - 1;
    const __hip_bfloat16* gb = Bw + (size_t)br * K + (k0 + kb * 8);
    LOAD_LDS16(gb, &SB[bsel][wave * 64]);
  };

  const int nk = K >> 5;
  stage(0, 0);
  __syncthreads();
  int buf = 0;
  for (int kt = 0; kt < nk; ++kt) {
    if (kt + 1 < nk) stage(buf ^ 1, (kt + 1) * 32);
    bf16x8 af[2], bq[2];
    #pragma unroll
    for (int f = 0; f < 2; ++f) {
      af[f] = SA[buf][lkb * 64 + wm + f * 16 + l15];
      bq[f] = SB[buf][lkb * 64 + wn + f * 16 + l15];
    }
    #pragma unroll
    for (int i = 0; i < 2; ++i)
      #pragma unroll
      for (int j = 0; j < 2; ++j)
        acc[i][j] = __builtin_amdgcn_mfma_f32_16x16x32_bf16(af[i], bq[j], acc[i][j], 0, 0, 0);
    __syncthreads();
    buf ^= 1;
  }

  #pragma unroll
  for (int i = 0; i < 2; ++i) {
    int r0 = m0 + wm + i * 16 + (lkb << 2);
    #pragma unroll
    for (int j = 0; j < 2; ++j) {
      int col = n0 + wn + j * 16 + l15;
      if (col >= N) continue;
      #pragma unroll
      for (int r = 0; r < 4; ++r) {
        int row = r0 + r;
        if (row >= M) continue;
        float v = acc[i][j][r];
        if (EPI >= 1) v += bias[col];
        if (EPI == 2) v *= aux[(size_t)row * N + col];
        if (EPI == 3) v = softplusf(v);
        if (EPI == 4) v *= aux[(size_t)(row % L_) * N + col];
        if (OF32) Cf[(size_t)row * N + col] = v;
        if (OBF)  Cb[(size_t)row * N + col] = __float2bfloat16(v);
      }
    }
  }
}

// ---------------------------------------------------------------------------
// MFMA GEMM 32x64 (4 waves x 16x32) — max parallelism for grid-starved links.
template<int EPI, bool OF32, bool OBF>
__global__ __launch_bounds__(256) void gemm32(
    const __hip_bfloat16* __restrict__ A, int lda, int M,
    const __hip_bfloat16* __restrict__ Bw, int Brows,
    const float* __restrict__ bias, const float* __restrict__ aux,
    float* __restrict__ Cf, __hip_bfloat16* __restrict__ Cb,
    int N, int K)
{
  __shared__ bf16x8 SA[2][128];   // [kb 0-3][row 0-31]
  __shared__ bf16x8 SB[2][256];   // [kb 0-3][row 0-63]
  const int tid = threadIdx.x;
  const int wave = tid >> 6, lane = tid & 63;
  const int m0 = blockIdx.y * 32, n0 = blockIdx.x * 64;
  const int wm = (wave >> 1) * 16, wn = (wave & 1) * 32;
  const int l15 = lane & 15, lkb = lane >> 4;

  f32x4 acc[2] = {};

  auto stage = [&](int bsel, int k0) {
    if (wave < 2) {
      int row = tid & 31, kb = tid >> 5;
      int ar = m0 + row; ar = ar < M ? ar : M - 1;
      const __hip_bfloat16* ga = A + (size_t)ar * lda + (k0 + kb * 8);
      LOAD_LDS16(ga, &SA[bsel][wave * 64]);
    } else {
      int t2 = tid - 128;
      {
        int row = t2 & 63, kb = t2 >> 6;
        int br = n0 + row; br = br < Brows ? br : Brows - 1;
        const __hip_bfloat16* gb = Bw + (size_t)br * K + (k0 + kb * 8);
        LOAD_LDS16(gb, &SB[bsel][(wave - 2) * 64]);
      }
      {
        int s1 = t2 + 128;
        int row = s1 & 63, kb = s1 >> 6;
        int br = n0 + row; br = br < Brows ? br : Brows - 1;
        const __hip_bfloat16* gb = Bw + (size_t)br * K + (k0 + kb * 8);
        LOAD_LDS16(gb, &SB[bsel][128 + (wave - 2) * 64]);
      }
    }
  };

  const int nk = K >> 5;
  stage(0, 0);
  __syncthreads();
  int buf = 0;
  for (int kt = 0; kt < nk; ++kt) {
    if (kt + 1 < nk) stage(buf ^ 1, (kt + 1) * 32);
    bf16x8 af = SA[buf][lkb * 32 + wm + l15];
    bf16x8 b0 = SB[buf][lkb * 64 + wn + l15];
    bf16x8 b1 = SB[buf][lkb * 64 + wn + 16 + l15];
    acc[0] = __builtin_amdgcn_mfma_f32_16x16x32_bf16(af, b0, acc[0], 0, 0, 0);
    acc[1] = __builtin_amdgcn_mfma_f32_16x16x32_bf16(af, b1, acc[1], 0, 0, 0);
    __syncthreads();
    buf ^= 1;
  }

  int r0 = m0 + wm + (lkb << 2);
  #pragma unroll
  for (int j = 0; j < 2; ++j) {
    int col = n0 + wn + j * 16 + l15;
    if (col >= N) continue;
    #pragma unroll
    for (int r = 0; r < 4; ++r) {
      int row = r0 + r;
      if (row >= M) continue;
      float v = acc[j][r];
      if (EPI >= 1) v += bias[col];
      if (EPI == 2) v *= aux[(size_t)row * N + col];
      if (EPI == 3) v = softplusf(v);
      if (EPI == 4) v *= aux[(size_t)(row % L_) * N + col];
      if (OF32) Cf[(size_t)row * N + col] = v;
      if (OBF)  Cb[(size_t)row * N + col] = __float2bfloat16(v);
    }
  }
}

// ---------------------------------------------------------------------------
// out_proj GEMM with fused A = (y_f+y_b)*silu(z), 16B staging loads.
__global__ __launch_bounds__(256) void gemm64_yz(
    const __hip_bfloat16* __restrict__ Y,   // [2][LB_][DI_]
    const __hip_bfloat16* __restrict__ Xz,  // [LB_][2*DI_] (z at +DI_)
    const __hip_bfloat16* __restrict__ Bw,  // [512][1024]
    __hip_bfloat16* __restrict__ Cb,        // [LB_][512]
    int M, int N, int K)
{
  __shared__ bf16x8 SA[2][256];
  __shared__ bf16x8 SB[2][256];
  const int tid = threadIdx.x;
  const int wave = tid >> 6, lane = tid & 63;
  const int m0 = blockIdx.y * 64, n0 = blockIdx.x * 64;
  const int wm = (wave >> 1) * 32, wn = (wave & 1) * 32;
  const int l15 = lane & 15, lkb = lane >> 4;

  f32x4 acc[2][2] = {};

  auto stage = [&](int bsel, int k0) {
    int row = tid & 63, kb = tid >> 6;
    int ar = m0 + row; ar = ar < M ? ar : M - 1;
    size_t o = (size_t)ar * DI_ + (k0 + kb * 8);
    u16x8 f8 = *(const u16x8*)(Y + o);
    u16x8 g8 = *(const u16x8*)(Y + LBDI_ + o);
    u16x8 z8 = *(const u16x8*)(Xz + (size_t)ar * (2 * DI_) + DI_ + (k0 + kb * 8));
    unsigned short av[8];
    #pragma unroll
    for (int q = 0; q < 8; ++q) {
      float v = (bf2f(f8[q]) + bf2f(g8[q])) * siluf(bf2f(z8[q]));
      av[q] = __bfloat16_as_ushort(__float2bfloat16(v));
    }
    SA[bsel][wave * 64 + row] = *(bf16x8*)av;
    int br = n0 + row; br = br < N ? br : N - 1;
    const __hip_bfloat16* gb = Bw + (size_t)br * K + (k0 + kb * 8);
    LOAD_LDS16(gb, &SB[bsel][wave * 64]);
  };

  const int nk = K >> 5;
  stage(0, 0);
  __syncthreads();
  int buf = 0;
  for (int kt = 0; kt < nk; ++kt) {
    if (kt + 1 < nk) stage(buf ^ 1, (kt + 1) * 32);
    bf16x8 af[2], bq[2];
    #pragma unroll
    for (int f = 0; f < 2; ++f) {
      af[f] = SA[buf][lkb * 64 + wm + f * 16 + l15];
      bq[f] = SB[buf][lkb * 64 + wn + f * 16 + l15];
    }
    #pragma unroll
    for (int i = 0; i < 2; ++i)
      #pragma unroll
      for (int j = 0; j < 2; ++j)
        acc[i][j] = __builtin_amdgcn_mfma_f32_16x16x32_bf16(af[i], bq[j], acc[i][j], 0, 0, 0);
    __syncthreads();
    buf ^= 1;
  }

  #pragma unroll
  for (int i = 0; i < 2; ++i) {
    int r0 = m0 + wm + i * 16 + (lkb << 2);
    #pragma unroll
    for (int j = 0; j < 2; ++j) {
      int col = n0 + wn + j * 16 + l15;
      if (col >= N) continue;
      #pragma unroll
      for (int r = 0; r < 4; ++r) {
        int row = r0 + r;
        if (row >= M) continue;
        Cb[(size_t)row * N + col] = __float2bfloat16(acc[i][j][r]);
      }
    }
  }
}

// ---------------------------------------------------------------------------
// Depthwise conv(k=4) + bias + silu, both directions; 4 channels per thread.
__global__ __launch_bounds__(256) void conv_silu(
    const __hip_bfloat16* __restrict__ xz, const float* __restrict__ w,
    const float* __restrict__ cb, __hip_bfloat16* __restrict__ xcbf)
{
  int t = blockIdx.x * 256 + threadIdx.x;
  int c4 = (t & (DI_ / 4 - 1)) * 4;
  int bl = t >> 8;
  int l = bl % L_;
  int b = bl / L_;
  const __hip_bfloat16* base = xz + (size_t)b * L_ * (2 * DI_) + c4;
  float xr[7][4];
  #pragma unroll
  for (int j = 0; j < 7; ++j) {
    int gl = l + j - 3;
    if (gl >= 0 && gl < L_) {
      u16x4 v = *(const u16x4*)(base + (size_t)gl * (2 * DI_));
      #pragma unroll
      for (int q = 0; q < 4; ++q) xr[j][q] = bf2f(v[q]);
    } else {
      #pragma unroll
      for (int q = 0; q < 4; ++q) xr[j][q] = 0.f;
    }
  }
  __hip_bfloat16 of[4], ob[4];
  #pragma unroll
  for (int q = 0; q < 4; ++q) {
    int c = c4 + q;
    float w0 = w[c * 4], w1 = w[c * 4 + 1], w2 = w[c * 4 + 2], w3 = w[c * 4 + 3];
    float bias = cb[c];
    float sf = fmaf(w0, xr[0][q], fmaf(w1, xr[1][q], fmaf(w2, xr[2][q], fmaf(w3, xr[3][q], bias))));
    float sb = fmaf(w0, xr[6][q], fmaf(w1, xr[5][q], fmaf(w2, xr[4][q], fmaf(w3, xr[3][q], bias))));
    of[q] = __float2bfloat16(siluf(sf));
    ob[q] = __float2bfloat16(siluf(sb));
  }
  size_t o = (size_t)bl * DI_ + c4;
  *(u16x4*)(xcbf + o)         = *(u16x4*)of;
  *(u16x4*)(xcbf + LBDI_ + o) = *(u16x4*)ob;
}

// ---------------------------------------------------------------------------
// Selective scan v11: v9 + partial unroll(4) so the compiler co-issues 4
// steps' independent loads (amortizes L2 latency). No per-step reg arrays.
#define SCT_ 24
#define HS_  17
__global__ __launch_bounds__(256) void scan_v11(
    const __hip_bfloat16* __restrict__ dtb, // [RT_][DI_] bf16
    const float* __restrict__ xd,           // [RT_][64]  f32
    const __hip_bfloat16* __restrict__ xc,  // [RT_][DI_] bf16
    const float* __restrict__ A_log, const float* __restrict__ Dv,
    __hip_bfloat16* __restrict__ y)         // [RT_][DI_] bf16
{
  __shared__ float sH[256 * HS_];
  __shared__ float sS[256];

  const int tid   = threadIdx.x;
  const int dl    = tid & 31;
  const int chunk = tid >> 5;
  const int dglob = blockIdx.x * 32 + dl;
  const int b     = blockIdx.y;
  const int dir   = blockIdx.z;
  const int rowbase = dir * LB_ + b * L_;
  const unsigned short* xcu = (const unsigned short*)xc;
  const unsigned short* dtu = (const unsigned short*)dtb;
  const float* Arow = A_log + dglob * 16;

  const float A0 = -__expf(Arow[0]);
  bool fast = true;
  #pragma unroll
  for (int s = 1; s < 16; ++s) {
    float As = -__expf(Arow[s]);
    fast = fast && (fabsf(As - (float)(s + 1) * A0) <= 1e-4f * (float)(s + 1));
  }
  const float Dd = Dv[dglob];

  const int cstart = chunk * SCT_;
  const int clen = (cstart + SCT_ <= L_) ? SCT_ : (L_ > cstart ? L_ - cstart : 0);

  auto powers = [&](float e1, float* ep) {
    ep[0] = e1;
    #pragma unroll
    for (int s = 1; s < 16; ++s) ep[s] = ep[(s - 1) >> 1] * ep[s >> 1];
  };

  // ---- pass 1: local scan from 0 ----
  float h[16];
  #pragma unroll
  for (int s = 0; s < 16; ++s) h[s] = 0.f;
  float dsum = 0.f;
  #pragma unroll 4
  for (int k = 0; k < clen; ++k) {
    int l   = cstart + k;
    int pos = dir ? (L_ - 1 - l) : l;
    size_t grow = (size_t)(rowbase + pos);
    float dtv = bf2f(dtu[grow * DI_ + dglob]);
    float xcv = bf2f(xcu[grow * DI_ + dglob]);
    float du  = dtv * xcv;
    dsum += dtv;
    const float* brow = xd + grow * 64;
    f32x4 bq0 = *(const f32x4*)(brow + 32);
    f32x4 bq1 = *(const f32x4*)(brow + 36);
    f32x4 bq2 = *(const f32x4*)(brow + 40);
    f32x4 bq3 = *(const f32x4*)(brow + 44);
    float ep[16];
    if (fast) {
      powers(__expf(dtv * A0), ep);
    } else {
      #pragma unroll
      for (int s = 0; s < 16; ++s) ep[s] = __expf(dtv * -__expf(Arow[s]));
    }
    #pragma unroll
    for (int s = 0; s < 16; ++s) {
      float Bv = (s < 4) ? bq0[s & 3] : (s < 8) ? bq1[s & 3] : (s < 12) ? bq2[s & 3] : bq3[s & 3];
      h[s] = fmaf(ep[s], h[s], du * Bv);
    }
  }
  {
    float* hr = sH + tid * HS_;
    #pragma unroll
    for (int s = 0; s < 16; ++s) hr[s] = h[s];
    sS[tid] = dsum;
  }
  __syncthreads();

  // ---- combine ----
  float hin[16];
  #pragma unroll
  for (int s = 0; s < 16; ++s) hin[s] = 0.f;
  for (int c = 0; c < chunk; ++c) {
    float S = sS[c * 32 + dl];
    const float* hp = sH + (c * 32 + dl) * HS_;
    float ep[16];
    if (fast) {
      powers(__expf(A0 * S), ep);
    } else {
      #pragma unroll
      for (int s = 0; s < 16; ++s) ep[s] = __expf(-__expf(Arow[s]) * S);
    }
    #pragma unroll
    for (int s = 0; s < 16; ++s)
      hin[s] = fmaf(ep[s], hin[s], hp[s]);
  }

  // ---- pass 2 ----
  #pragma unroll
  for (int s = 0; s < 16; ++s) h[s] = hin[s];
  #pragma unroll 4
  for (int k = 0; k < clen; ++k) {
    int l   = cstart + k;
    int pos = dir ? (L_ - 1 - l) : l;
    size_t grow = (size_t)(rowbase + pos);
    float dtv = bf2f(dtu[grow * DI_ + dglob]);
    float xcv = bf2f(xcu[grow * DI_ + dglob]);
    float du  = dtv * xcv;
    const float* brow = xd + grow * 64;
    f32x4 bq0 = *(const f32x4*)(brow + 32);
    f32x4 bq1 = *(const f32x4*)(brow + 36);
    f32x4 bq2 = *(const f32x4*)(brow + 40);
    f32x4 bq3 = *(const f32x4*)(brow + 44);
    f32x4 cq0 = *(const f32x4*)(brow + 48);
    f32x4 cq1 = *(const f32x4*)(brow + 52);
    f32x4 cq2 = *(const f32x4*)(brow + 56);
    f32x4 cq3 = *(const f32x4*)(brow + 60);
    float ep[16];
    if (fast) {
      powers(__expf(dtv * A0), ep);
    } else {
      #pragma unroll
      for (int s = 0; s < 16; ++s) ep[s] = __expf(dtv * -__expf(Arow[s]));
    }
    float acc = 0.f;
    #pragma unroll
    for (int s = 0; s < 16; ++s) {
      float Bv = (s < 4) ? bq0[s & 3] : (s < 8) ? bq1[s & 3] : (s < 12) ? bq2[s & 3] : bq3[s & 3];
      float Cv = (s < 4) ? cq0[s & 3] : (s < 8) ? cq1[s & 3] : (s < 12) ? cq2[s & 3] : cq3[s & 3];
      h[s] = fmaf(ep[s], h[s], du * Bv);
      acc  = fmaf(h[s], Cv, acc);
    }
    y[grow * DI_ + dglob] = __float2bfloat16(fmaf(xcv, Dd, acc));
  }
}

// ---------------------------------------------------------------------------
__global__ __launch_bounds__(256) void ln_final(const float* __restrict__ x,
    const float* __restrict__ partials,
    const float* __restrict__ nw, const float* __restrict__ nb,
    float* __restrict__ out)
{
  int b = blockIdx.y, ch = blockIdx.x;
  float S = 0.f, S2 = 0.f;
  #pragma unroll
  for (int i = 0; i < 8; ++i) { S += partials[(b * 8 + i) * 2 + 0]; S2 += partials[(b * 8 + i) * 2 + 1]; }
  const float inv = 1.f / (float)(L_ * DM_);
  float mu = S * inv;
  float var = S2 * inv - mu * mu;
  float r = rsqrtf(var + 1e-5f);
  const float* xb = x + (size_t)b * (L_ * DM_);
  float* ob = out + (size_t)b * (L_ * DM_);
  int lo = ch * 12160, hi = lo + 12160;
  for (int i = lo + threadIdx.x; i < hi; i += 256) {
    float t = tanhf(xb[i]);
    ob[i] = fmaf((t - mu) * r, nw[i], nb[i]);
  }
}

// ---------------------------------------------------------------------------
extern "C" void kernel_launch(void* const* d_in, const int* in_sizes, int n_in,
                              void* d_out, int out_size, void* d_ws, size_t ws_size,
                              hipStream_t stream)
{
  const float* x            = (const float*)d_in[0];
  const void*  pc_mask      = d_in[1];
  const float* in_resize_w  = (const float*)d_in[2];
  const float* in_resize_b  = (const float*)d_in[3];
  const float* in_reset_w   = (const float*)d_in[4];
  const float* in_reset_b   = (const float*)d_in[5];
  const float* out_resize_w = (const float*)d_in[6];
  const float* out_resize_b = (const float*)d_in[7];
  const float* out_reset_w  = (const float*)d_in[8];
  const float* out_reset_b  = (const float*)d_in[9];
  const float* in_proj_w    = (const float*)d_in[10];
  const float* conv_w       = (const float*)d_in[11];
  const float* conv_b       = (const float*)d_in[12];
  const float* x_proj_w     = (const float*)d_in[13];
  const float* dt_proj_w    = (const float*)d_in[14];
  const float* dt_proj_b    = (const float*)d_in[15];
  const float* A_log        = (const float*)d_in[16];
  const float* Dv           = (const float*)d_in[17];
  const float* out_proj_w   = (const float*)d_in[18];
  const float* norm_w       = (const float*)d_in[19];
  const float* norm_b       = (const float*)d_in[20];

  // ---- workspace ----
  float* W = (float*)d_ws;
  float* maskf    = W + 0;        // 36480
  float* b_comb   = W + 36480;    // 512
  float* b_outrs  = W + 36992;    // 192
  float* xd       = W + 37184;    // 389120
  float* partials = W + 426304;   // 256
  __hip_bfloat16* BF = (__hip_bfloat16*)(W + 426560);
  __hip_bfloat16* w_inrt  = BF + 0;         // 512*192
  __hip_bfloat16* w_inpj  = BF + 98304;     // 2048*512
  __hip_bfloat16* w_xpj   = BF + 1146880;   // 64*1024
  __hip_bfloat16* w_dtpj  = BF + 1212416;   // 1024*32
  __hip_bfloat16* w_outpj = BF + 1245184;   // 512*1024
  __hip_bfloat16* w_outrs = BF + 1769472;   // 192*512
  __hip_bfloat16* w_outrt = BF + 1867776;   // 512*192
  __hip_bfloat16* w_inrsT = BF + 1966080;   // 512*192 (in_resize_w transposed)
  __hip_bfloat16* wcomb   = BF + 2064384;   // 512*512
  __hip_bfloat16* h_bf    = BF + 2326528;   // 3040*512
  __hip_bfloat16* xz_bf   = BF + 3883008;   // 3040*2048
  __hip_bfloat16* xc_bf   = BF + 10108928;  // 2*3040*1024
  __hip_bfloat16* y_bf    = BF + 16334848;  // 2*3040*1024
  __hip_bfloat16* xd_bf   = BF + 22560768;  // 6080*64
  __hip_bfloat16* dt_bf   = BF + 22949888;  // 6080*1024
  __hip_bfloat16* o_pre   = BF + 29175808;  // 3040*512
  __hip_bfloat16* o2_bf   = BF + 30732288;  // 3040*192

  float* out_ln = (float*)d_out;
  float* out_o  = (float*)d_out + (size_t)LB_ * DM_;

  dim3 blk(256);

  CvtPack2 P;
  P.d[0] = Cvt2{ in_reset_w,   w_inrt,  512, 190, 512, 192, 0 };
  P.d[1] = Cvt2{ in_proj_w,    w_inpj,  2048, 512, 2048, 512, 0 };
  P.d[2] = Cvt2{ x_proj_w,     w_xpj,   64, 1024, 64, 1024, 0 };
  P.d[3] = Cvt2{ dt_proj_w,    w_dtpj,  1024, 32, 1024, 32, 0 };
  P.d[4] = Cvt2{ out_proj_w,   w_outpj, 512, 1024, 512, 1024, 0 };
  P.d[5] = Cvt2{ out_resize_w, w_outrs, 190, 512, 192, 512, 0 };
  P.d[6] = Cvt2{ out_reset_w,  w_outrt, 512, 190, 512, 192, 0 };
  P.d[7] = Cvt2{ in_resize_w,  w_inrsT, 512, 190, 512, 192, 1 };  // transposed
  cvt_all4<<<dim3(256, 11), blk, 0, stream>>>(P, pc_mask, maskf,
      in_resize_b, out_resize_b, b_outrs,
      in_reset_w, in_reset_b, b_comb, x, partials);

  // Wcomb = in_reset_w @ in_resize_w  (512x512, K=192)
  gemm32<0,false,true><<<dim3(8,16), blk, 0, stream>>>(w_inrt, 192, 512, w_inrsT, 512, nullptr, nullptr, nullptr, wcomb, 512, 192);
  // h = (x @ Wcomb^T + b_comb) * x   [folded h1+h; A is f32, reg-staged]
  gemm64<2,false,true,true><<<dim3(8,48), blk, 0, stream>>>((const __hip_bfloat16*)x, 512, 3040, wcomb, 512, b_comb, x, nullptr, h_bf, 512, 512);
  // xz = h @ in_proj_w^T
  gemm128<0,false,true><<<dim3(16,24), blk, 0, stream>>>(h_bf, 512, 3040, w_inpj, 2048, nullptr, nullptr, nullptr, xz_bf, 2048, 512);
  // conv + silu (both dirs)
  conv_silu<<<dim3(LBDI_/1024), blk, 0, stream>>>(xz_bf, conv_w, conv_b, xc_bf);
  // x_dbl = xc @ x_proj_w^T  (M=6080, N=64, K=1024) -> xd f32 + xd_bf
  gemm32<0,true,true><<<dim3(1,190), blk, 0, stream>>>(xc_bf, 1024, 6080, w_xpj, 64, nullptr, nullptr, xd, xd_bf, 64, 1024);
  // dt = softplus(x_dbl[:,:32] @ dt_proj_w^T + b) -> bf16
  gemm64<3,false,true,false><<<dim3(16,95), blk, 0, stream>>>(xd_bf, 64, 6080, w_dtpj, 1024, dt_proj_b, nullptr, nullptr, dt_bf, 1024, 32);
  // selective scan
  scan_v11<<<dim3(32, 16, 2), blk, 0, stream>>>(dt_bf, xd, xc_bf, A_log, Dv, y_bf);
  // o_pre = ((y_f+y_b)*silu(z)) @ out_proj_w^T
  gemm64_yz<<<dim3(8,48), blk, 0, stream>>>(y_bf, xz_bf, w_outpj, o_pre, 3040, 512, 1024);
  // o2 = (o_pre @ out_resize_w^T + b) * mask[l,:]
  gemm32<4,false,true><<<dim3(3,95), blk, 0, stream>>>(o_pre, 512, 3040, w_outrs, 192, b_outrs, maskf, nullptr, o2_bf, LP_, 512);
  // o = (o2 @ out_reset_w^T + b) * x  -> output 1
  gemm64<2,true,false,false><<<dim3(8,48), blk, 0, stream>>>(o2_bf, LP_, 3040, w_outrt, 512, out_reset_b, x, out_o, nullptr, 512, LP_);
  // output 0: layernorm(tanh(x)); partials computed in cvt_all4
  ln_final<<<dim3(8, B_), blk, 0, stream>>>(x, partials, norm_w, norm_b, out_ln);
}

// Round 14
// 269.242 us; speedup vs baseline: 2.1468x; 1.0119x over previous
//
#include <hip/hip_runtime.h>
#include <hip/hip_bf16.h>

#define B_    16
#define L_    190
#define LP_   192        // padded L
#define DM_   512
#define DI_   1024
#define LB_   3040       // B_*L_
#define RT_   6080       // 2*LB_ rows (dir-major)
#define LBDI_ 3112960    // LB_*DI_

typedef __attribute__((ext_vector_type(8))) short bf16x8;
typedef __attribute__((ext_vector_type(4))) float f32x4;
typedef __attribute__((ext_vector_type(4))) unsigned short u16x4;
typedef __attribute__((ext_vector_type(8))) unsigned short u16x8;

typedef const __attribute__((address_space(1))) void gvoid;
typedef __attribute__((address_space(3))) void lvoid;
#define LOAD_LDS16(g, l) __builtin_amdgcn_global_load_lds((gvoid*)(g), (lvoid*)(l), 16, 0, 0)

__device__ __forceinline__ float siluf(float v) { return v / (1.f + __expf(-v)); }
__device__ __forceinline__ float softplusf(float v) {
  return v > 0.f ? v + log1pf(__expf(-v)) : log1pf(__expf(v));
}
__device__ __forceinline__ float bf2f(unsigned short u) {
  unsigned int w = (unsigned int)u << 16; return __builtin_bit_cast(float, w);
}

// ---------------------------------------------------------------------------
// Segments 0-7: f32 -> padded bf16 (seg 7 transposed). y==8: mask + b_outrs.
// y==9: bias_comb = in_reset_w @ in_resize_b + in_reset_b. y==10: ln_partial.
struct Cvt2 { const float* src; __hip_bfloat16* dst; int R, C, Rp, Cp, T; };
struct CvtPack2 { Cvt2 d[8]; };

__global__ __launch_bounds__(256) void cvt_all4(CvtPack2 p,
    const void* __restrict__ pcm, float* __restrict__ maskf,
    const float* __restrict__ irb, const float* __restrict__ orb,
    float* __restrict__ b_outrs,
    const float* __restrict__ irw, const float* __restrict__ irtb,
    float* __restrict__ b_comb,
    const float* __restrict__ x, float* __restrict__ partials)
{
  if (blockIdx.y == 8) {
    __shared__ int votes[3];
    if (threadIdx.x < 3) votes[threadIdx.x] = 0;
    __syncthreads();
    if (threadIdx.x < 48) {
      int idx = threadIdx.x * 191;
      const unsigned char* p8  = (const unsigned char*)pcm;
      const unsigned int*  p32 = (const unsigned int*)pcm;
      if (p8[idx] == 1) atomicAdd(&votes[0], 1);
      unsigned int v = p32[idx];
      if (v == 1u)          atomicAdd(&votes[1], 1);
      if (v == 0x3f800000u) atomicAdd(&votes[2], 1);
    }
    __syncthreads();
    int mode = (votes[0] >= 48) ? 0 : (votes[1] >= 48 ? 1 : (votes[2] >= 48 ? 2 : 0));
    for (int i = blockIdx.x * 256 + threadIdx.x; i < L_ * LP_; i += gridDim.x * 256) {
      int r = i / LP_, c = i % LP_;
      float v = 0.f;
      if (c < L_) {
        int s = r * L_ + c;
        if (mode == 0)      v = ((const unsigned char*)pcm)[s] ? 1.f : 0.f;
        else if (mode == 1) v = ((const int*)pcm)[s] ? 1.f : 0.f;
        else                v = ((const float*)pcm)[s];
      }
      maskf[i] = v;
    }
    if (blockIdx.x == 0 && threadIdx.x < LP_)
      b_outrs[threadIdx.x] = (threadIdx.x < L_) ? orb[threadIdx.x] : 0.f;
    return;
  }
  if (blockIdx.y == 9) {
    if (blockIdx.x < 2) {
      int n = blockIdx.x * 256 + threadIdx.x;   // < 512
      const float* wrow = irw + (size_t)n * L_;
      float s = 0.f;
      for (int k = 0; k < L_; ++k) s = fmaf(wrow[k], irb[k], s);
      b_comb[n] = s + irtb[n];
    }
    return;
  }
  if (blockIdx.y == 10) {
    if (blockIdx.x < 128) {
      int bb = blockIdx.x >> 3, ch = blockIdx.x & 7;
      const float* xb = x + (size_t)bb * (L_ * DM_);
      int lo = ch * 12160, hi = lo + 12160;
      float s = 0.f, s2 = 0.f;
      for (int i = lo + threadIdx.x; i < hi; i += 256) {
        float t = tanhf(xb[i]);
        s += t; s2 = fmaf(t, t, s2);
      }
      #pragma unroll
      for (int off = 32; off > 0; off >>= 1) { s += __shfl_down(s, off); s2 += __shfl_down(s2, off); }
      __shared__ float rs[4], rs2[4];
      int wid = threadIdx.x >> 6, lane = threadIdx.x & 63;
      if (lane == 0) { rs[wid] = s; rs2[wid] = s2; }
      __syncthreads();
      if (threadIdx.x == 0) {
        partials[(bb * 8 + ch) * 2 + 0] = rs[0] + rs[1] + rs[2] + rs[3];
        partials[(bb * 8 + ch) * 2 + 1] = rs2[0] + rs2[1] + rs2[2] + rs2[3];
      }
    }
    return;
  }
  Cvt2 D = p.d[blockIdx.y];
  int n = D.Rp * D.Cp;
  if (D.T) {
    for (int i = blockIdx.x * 256 + threadIdx.x; i < n; i += gridDim.x * 256) {
      int r = i / D.Cp, c = i - r * D.Cp;
      float v = (c < D.C && r < D.R) ? D.src[(size_t)c * D.R + r] : 0.f;
      D.dst[i] = __float2bfloat16(v);
    }
  } else if (D.C == D.Cp) {
    int nsrc = D.R * D.C;
    for (int i4 = (blockIdx.x * 256 + threadIdx.x) * 4; i4 < n; i4 += gridDim.x * 256 * 4) {
      __hip_bfloat16 o[4];
      if (i4 + 3 < nsrc) {
        f32x4 v = *(const f32x4*)(D.src + i4);
        #pragma unroll
        for (int q = 0; q < 4; ++q) o[q] = __float2bfloat16(v[q]);
      } else {
        #pragma unroll
        for (int q = 0; q < 4; ++q) { int i = i4 + q; o[q] = __float2bfloat16(i < nsrc ? D.src[i] : 0.f); }
      }
      *(u16x4*)(D.dst + i4) = *(u16x4*)o;
    }
  } else {
    for (int i = blockIdx.x * 256 + threadIdx.x; i < n; i += gridDim.x * 256) {
      int r = i / D.Cp, c = i - r * D.Cp;
      float v = (r < D.R && c < D.C) ? D.src[(size_t)r * D.C + c] : 0.f;
      D.dst[i] = __float2bfloat16(v);
    }
  }
}

// ---------------------------------------------------------------------------
// MFMA GEMM 128x128 (4 waves x 64x64). EPI: 0 none | 1 +bias | 2 (+bias)*aux |
// 3 softplus | 4 (+bias)*aux[(m%190)*N+n]
template<int EPI, bool OF32, bool OBF>
__global__ __launch_bounds__(256) void gemm128(
    const __hip_bfloat16* __restrict__ A, int lda, int M,
    const __hip_bfloat16* __restrict__ Bw, int Brows,
    const float* __restrict__ bias, const float* __restrict__ aux,
    float* __restrict__ Cf, __hip_bfloat16* __restrict__ Cb,
    int N, int K)
{
  __shared__ bf16x8 SA[2][512];
  __shared__ bf16x8 SB[2][512];
  const int tid = threadIdx.x;
  const int wave = tid >> 6, lane = tid & 63;
  const int m0 = blockIdx.y * 128, n0 = blockIdx.x * 128;
  const int wm = (wave >> 1) * 64, wn = (wave & 1) * 64;
  const int l15 = lane & 15, lkb = lane >> 4;

  f32x4 acc[4][4] = {};

  auto stage = [&](int bsel, int k0) {
    #pragma unroll
    for (int it = 0; it < 2; ++it) {
      int c = it * 256 + tid;
      int row = c & 127, kb = c >> 7;
      int ar = m0 + row; ar = ar < M ? ar : M - 1;
      const __hip_bfloat16* ga = A + (size_t)ar * lda + (k0 + kb * 8);
      LOAD_LDS16(ga, &SA[bsel][it * 256 + wave * 64]);
      int br = n0 + row; br = br < Brows ? br : Brows - 1;
      const __hip_bfloat16* gb = Bw + (size_t)br * K + (k0 + kb * 8);
      LOAD_LDS16(gb, &SB[bsel][it * 256 + wave * 64]);
    }
  };

  const int nk = K >> 5;
  stage(0, 0);
  __syncthreads();
  int buf = 0;
  for (int kt = 0; kt < nk; ++kt) {
    if (kt + 1 < nk) stage(buf ^ 1, (kt + 1) * 32);
    bf16x8 af[4], bq[4];
    #pragma unroll
    for (int f = 0; f < 4; ++f) {
      af[f] = SA[buf][lkb * 128 + wm + f * 16 + l15];
      bq[f] = SB[buf][lkb * 128 + wn + f * 16 + l15];
    }
    #pragma unroll
    for (int i = 0; i < 4; ++i)
      #pragma unroll
      for (int j = 0; j < 4; ++j)
        acc[i][j] = __builtin_amdgcn_mfma_f32_16x16x32_bf16(af[i], bq[j], acc[i][j], 0, 0, 0);
    __syncthreads();
    buf ^= 1;
  }

  #pragma unroll
  for (int i = 0; i < 4; ++i) {
    int r0 = m0 + wm + i * 16 + (lkb << 2);
    #pragma unroll
    for (int j = 0; j < 4; ++j) {
      int col = n0 + wn + j * 16 + l15;
      if (col >= N) continue;
      #pragma unroll
      for (int r = 0; r < 4; ++r) {
        int row = r0 + r;
        if (row >= M) continue;
        float v = acc[i][j][r];
        if (EPI >= 1) v += bias[col];
        if (EPI == 2) v *= aux[(size_t)row * N + col];
        if (EPI == 3) v = softplusf(v);
        if (EPI == 4) v *= aux[(size_t)(row % L_) * N + col];
        if (OF32) Cf[(size_t)row * N + col] = v;
        if (OBF)  Cb[(size_t)row * N + col] = __float2bfloat16(v);
      }
    }
  }
}

// ---------------------------------------------------------------------------
// MFMA GEMM 64x64 (4 waves x 32x32). AF32: A is f32, reg-staged + converted.
template<int EPI, bool OF32, bool OBF, bool AF32>
__global__ __launch_bounds__(256) void gemm64(
    const __hip_bfloat16* __restrict__ A, int lda, int M,
    const __hip_bfloat16* __restrict__ Bw, int Brows,
    const float* __restrict__ bias, const float* __restrict__ aux,
    float* __restrict__ Cf, __hip_bfloat16* __restrict__ Cb,
    int N, int K)
{
  __shared__ bf16x8 SA[2][256];
  __shared__ bf16x8 SB[2][256];
  const int tid = threadIdx.x;
  const int wave = tid >> 6, lane = tid & 63;
  const int m0 = blockIdx.y * 64, n0 = blockIdx.x * 64;
  const int wm = (wave >> 1) * 32, wn = (wave & 1) * 32;
  const int l15 = lane & 15, lkb = lane >> 4;

  f32x4 acc[2][2] = {};

  auto stage = [&](int bsel, int k0) {
    int row = tid & 63, kb = tid >> 6;
    int ar = m0 + row; ar = ar < M ? ar : M - 1;
    if (AF32) {
      const float* ga = (const float*)A + (size_t)ar * lda + (k0 + kb * 8);
      f32x4 v0 = *(const f32x4*)ga;
      f32x4 v1 = *(const f32x4*)(ga + 4);
      __hip_bfloat16 o[8];
      #pragma unroll
      for (int q = 0; q < 4; ++q) { o[q] = __float2bfloat16(v0[q]); o[q + 4] = __float2bfloat16(v1[q]); }
      SA[bsel][wave * 64 + row] = *(bf16x8*)o;
    } else {
      const __hip_bfloat16* ga = A + (size_t)ar * lda + (k0 + kb * 8);
      LOAD_LDS16(ga, &SA[bsel][wave * 64]);
    }
    int br = n0 + row; br = br < Brows ? br : Brows - 1;
    const __hip_bfloat16* gb = Bw + (size_t)br * K + (k0 + kb * 8);
    LOAD_LDS16(gb, &SB[bsel][wave * 64]);
  };

  const int nk = K >> 5;
  stage(0, 0);
  __syncthreads();
  int buf = 0;
  for (int kt = 0; kt < nk; ++kt) {
    if (kt + 1 < nk) stage(buf ^ 1, (kt + 1) * 32);
    bf16x8 af[2], bq[2];
    #pragma unroll
    for (int f = 0; f < 2; ++f) {
      af[f] = SA[buf][lkb * 64 + wm + f * 16 + l15];
      bq[f] = SB[buf][lkb * 64 + wn + f * 16 + l15];
    }
    #pragma unroll
    for (int i = 0; i < 2; ++i)
      #pragma unroll
      for (int j = 0; j < 2; ++j)
        acc[i][j] = __builtin_amdgcn_mfma_f32_16x16x32_bf16(af[i], bq[j], acc[i][j], 0, 0, 0);
    __syncthreads();
    buf ^= 1;
  }

  #pragma unroll
  for (int i = 0; i < 2; ++i) {
    int r0 = m0 + wm + i * 16 + (lkb << 2);
    #pragma unroll
    for (int j = 0; j < 2; ++j) {
      int col = n0 + wn + j * 16 + l15;
      if (col >= N) continue;
      #pragma unroll
      for (int r = 0; r < 4; ++r) {
        int row = r0 + r;
        if (row >= M) continue;
        float v = acc[i][j][r];
        if (EPI >= 1) v += bias[col];
        if (EPI == 2) v *= aux[(size_t)row * N + col];
        if (EPI == 3) v = softplusf(v);
        if (EPI == 4) v *= aux[(size_t)(row % L_) * N + col];
        if (OF32) Cf[(size_t)row * N + col] = v;
        if (OBF)  Cb[(size_t)row * N + col] = __float2bfloat16(v);
      }
    }
  }
}

// ---------------------------------------------------------------------------
// MFMA GEMM 32x64 (4 waves x 16x32) — max parallelism for grid-starved links.
template<int EPI, bool OF32, bool OBF>
__global__ __launch_bounds__(256) void gemm32(
    const __hip_bfloat16* __restrict__ A, int lda, int M,
    const __hip_bfloat16* __restrict__ Bw, int Brows,
    const float* __restrict__ bias, const float* __restrict__ aux,
    float* __restrict__ Cf, __hip_bfloat16* __restrict__ Cb,
    int N, int K)
{
  __shared__ bf16x8 SA[2][128];
  __shared__ bf16x8 SB[2][256];
  const int tid = threadIdx.x;
  const int wave = tid >> 6, lane = tid & 63;
  const int m0 = blockIdx.y * 32, n0 = blockIdx.x * 64;
  const int wm = (wave >> 1) * 16, wn = (wave & 1) * 32;
  const int l15 = lane & 15, lkb = lane >> 4;

  f32x4 acc[2] = {};

  auto stage = [&](int bsel, int k0) {
    if (wave < 2) {
      int row = tid & 31, kb = tid >> 5;
      int ar = m0 + row; ar = ar < M ? ar : M - 1;
      const __hip_bfloat16* ga = A + (size_t)ar * lda + (k0 + kb * 8);
      LOAD_LDS16(ga, &SA[bsel][wave * 64]);
    } else {
      int t2 = tid - 128;
      {
        int row = t2 & 63, kb = t2 >> 6;
        int br = n0 + row; br = br < Brows ? br : Brows - 1;
        const __hip_bfloat16* gb = Bw + (size_t)br * K + (k0 + kb * 8);
        LOAD_LDS16(gb, &SB[bsel][(wave - 2) * 64]);
      }
      {
        int s1 = t2 + 128;
        int row = s1 & 63, kb = s1 >> 6;
        int br = n0 + row; br = br < Brows ? br : Brows - 1;
        const __hip_bfloat16* gb = Bw + (size_t)br * K + (k0 + kb * 8);
        LOAD_LDS16(gb, &SB[bsel][128 + (wave - 2) * 64]);
      }
    }
  };

  const int nk = K >> 5;
  stage(0, 0);
  __syncthreads();
  int buf = 0;
  for (int kt = 0; kt < nk; ++kt) {
    if (kt + 1 < nk) stage(buf ^ 1, (kt + 1) * 32);
    bf16x8 af = SA[buf][lkb * 32 + wm + l15];
    bf16x8 b0 = SB[buf][lkb * 64 + wn + l15];
    bf16x8 b1 = SB[buf][lkb * 64 + wn + 16 + l15];
    acc[0] = __builtin_amdgcn_mfma_f32_16x16x32_bf16(af, b0, acc[0], 0, 0, 0);
    acc[1] = __builtin_amdgcn_mfma_f32_16x16x32_bf16(af, b1, acc[1], 0, 0, 0);
    __syncthreads();
    buf ^= 1;
  }

  int r0 = m0 + wm + (lkb << 2);
  #pragma unroll
  for (int j = 0; j < 2; ++j) {
    int col = n0 + wn + j * 16 + l15;
    if (col >= N) continue;
    #pragma unroll
    for (int r = 0; r < 4; ++r) {
      int row = r0 + r;
      if (row >= M) continue;
      float v = acc[j][r];
      if (EPI >= 1) v += bias[col];
      if (EPI == 2) v *= aux[(size_t)row * N + col];
      if (EPI == 3) v = softplusf(v);
      if (EPI == 4) v *= aux[(size_t)(row % L_) * N + col];
      if (OF32) Cf[(size_t)row * N + col] = v;
      if (OBF)  Cb[(size_t)row * N + col] = __float2bfloat16(v);
    }
  }
}

// ---------------------------------------------------------------------------
// out_proj GEMM with fused A = (y_f+y_b)*silu(z), 16B staging loads.
__global__ __launch_bounds__(256) void gemm64_yz(
    const __hip_bfloat16* __restrict__ Y,
    const __hip_bfloat16* __restrict__ Xz,
    const __hip_bfloat16* __restrict__ Bw,
    __hip_bfloat16* __restrict__ Cb,
    int M, int N, int K)
{
  __shared__ bf16x8 SA[2][256];
  __shared__ bf16x8 SB[2][256];
  const int tid = threadIdx.x;
  const int wave = tid >> 6, lane = tid & 63;
  const int m0 = blockIdx.y * 64, n0 = blockIdx.x * 64;
  const int wm = (wave >> 1) * 32, wn = (wave & 1) * 32;
  const int l15 = lane & 15, lkb = lane >> 4;

  f32x4 acc[2][2] = {};

  auto stage = [&](int bsel, int k0) {
    int row = tid & 63, kb = tid >> 6;
    int ar = m0 + row; ar = ar < M ? ar : M - 1;
    size_t o = (size_t)ar * DI_ + (k0 + kb * 8);
    u16x8 f8 = *(const u16x8*)(Y + o);
    u16x8 g8 = *(const u16x8*)(Y + LBDI_ + o);
    u16x8 z8 = *(const u16x8*)(Xz + (size_t)ar * (2 * DI_) + DI_ + (k0 + kb * 8));
    unsigned short av[8];
    #pragma unroll
    for (int q = 0; q < 8; ++q) {
      float v = (bf2f(f8[q]) + bf2f(g8[q])) * siluf(bf2f(z8[q]));
      av[q] = __bfloat16_as_ushort(__float2bfloat16(v));
    }
    SA[bsel][wave * 64 + row] = *(bf16x8*)av;
    int br = n0 + row; br = br < N ? br : N - 1;
    const __hip_bfloat16* gb = Bw + (size_t)br * K + (k0 + kb * 8);
    LOAD_LDS16(gb, &SB[bsel][wave * 64]);
  };

  const int nk = K >> 5;
  stage(0, 0);
  __syncthreads();
  int buf = 0;
  for (int kt = 0; kt < nk; ++kt) {
    if (kt + 1 < nk) stage(buf ^ 1, (kt + 1) * 32);
    bf16x8 af[2], bq[2];
    #pragma unroll
    for (int f = 0; f < 2; ++f) {
      af[f] = SA[buf][lkb * 64 + wm + f * 16 + l15];
      bq[f] = SB[buf][lkb * 64 + wn + f * 16 + l15];
    }
    #pragma unroll
    for (int i = 0; i < 2; ++i)
      #pragma unroll
      for (int j = 0; j < 2; ++j)
        acc[i][j] = __builtin_amdgcn_mfma_f32_16x16x32_bf16(af[i], bq[j], acc[i][j], 0, 0, 0);
    __syncthreads();
    buf ^= 1;
  }

  #pragma unroll
  for (int i = 0; i < 2; ++i) {
    int r0 = m0 + wm + i * 16 + (lkb << 2);
    #pragma unroll
    for (int j = 0; j < 2; ++j) {
      int col = n0 + wn + j * 16 + l15;
      if (col >= N) continue;
      #pragma unroll
      for (int r = 0; r < 4; ++r) {
        int row = r0 + r;
        if (row >= M) continue;
        Cb[(size_t)row * N + col] = __float2bfloat16(acc[i][j][r]);
      }
    }
  }
}

// ---------------------------------------------------------------------------
// Depthwise conv(k=4) + bias + silu, both directions; 4 channels per thread.
__global__ __launch_bounds__(256) void conv_silu(
    const __hip_bfloat16* __restrict__ xz, const float* __restrict__ w,
    const float* __restrict__ cb, __hip_bfloat16* __restrict__ xcbf)
{
  int t = blockIdx.x * 256 + threadIdx.x;
  int c4 = (t & (DI_ / 4 - 1)) * 4;
  int bl = t >> 8;
  int l = bl % L_;
  int b = bl / L_;
  const __hip_bfloat16* base = xz + (size_t)b * L_ * (2 * DI_) + c4;
  float xr[7][4];
  #pragma unroll
  for (int j = 0; j < 7; ++j) {
    int gl = l + j - 3;
    if (gl >= 0 && gl < L_) {
      u16x4 v = *(const u16x4*)(base + (size_t)gl * (2 * DI_));
      #pragma unroll
      for (int q = 0; q < 4; ++q) xr[j][q] = bf2f(v[q]);
    } else {
      #pragma unroll
      for (int q = 0; q < 4; ++q) xr[j][q] = 0.f;
    }
  }
  __hip_bfloat16 of[4], ob[4];
  #pragma unroll
  for (int q = 0; q < 4; ++q) {
    int c = c4 + q;
    float w0 = w[c * 4], w1 = w[c * 4 + 1], w2 = w[c * 4 + 2], w3 = w[c * 4 + 3];
    float bias = cb[c];
    float sf = fmaf(w0, xr[0][q], fmaf(w1, xr[1][q], fmaf(w2, xr[2][q], fmaf(w3, xr[3][q], bias))));
    float sb = fmaf(w0, xr[6][q], fmaf(w1, xr[5][q], fmaf(w2, xr[4][q], fmaf(w3, xr[3][q], bias))));
    of[q] = __float2bfloat16(siluf(sf));
    ob[q] = __float2bfloat16(siluf(sb));
  }
  size_t o = (size_t)bl * DI_ + c4;
  *(u16x4*)(xcbf + o)         = *(u16x4*)of;
  *(u16x4*)(xcbf + LBDI_ + o) = *(u16x4*)ob;
}

// ---------------------------------------------------------------------------
// Selective scan v12: 512-thread block = 32 d-lanes x 16 chunks of 12.
// 8 waves/block, 4 blocks/CU (LDS 36.9KB) -> 32 waves/CU. v9 codegen style:
// runtime loops, no per-step reg arrays, log-depth powers.
#define SCT_ 12
#define HS_  17
__global__ __launch_bounds__(512) void scan_v12(
    const __hip_bfloat16* __restrict__ dtb, // [RT_][DI_] bf16
    const float* __restrict__ xd,           // [RT_][64]  f32
    const __hip_bfloat16* __restrict__ xc,  // [RT_][DI_] bf16
    const float* __restrict__ A_log, const float* __restrict__ Dv,
    __hip_bfloat16* __restrict__ y)         // [RT_][DI_] bf16
{
  __shared__ float sH[512 * HS_];    // 34816 B
  __shared__ float sS[512];          //  2048 B

  const int tid   = threadIdx.x;
  const int dl    = tid & 31;
  const int chunk = tid >> 5;        // 0..15
  const int dglob = blockIdx.x * 32 + dl;
  const int b     = blockIdx.y;
  const int dir   = blockIdx.z;
  const int rowbase = dir * LB_ + b * L_;
  const unsigned short* xcu = (const unsigned short*)xc;
  const unsigned short* dtu = (const unsigned short*)dtb;
  const float* Arow = A_log + dglob * 16;

  const float A0 = -__expf(Arow[0]);
  bool fast = true;
  #pragma unroll
  for (int s = 1; s < 16; ++s) {
    float As = -__expf(Arow[s]);
    fast = fast && (fabsf(As - (float)(s + 1) * A0) <= 1e-4f * (float)(s + 1));
  }
  const float Dd = Dv[dglob];

  const int cstart = chunk * SCT_;
  const int clen = (cstart + SCT_ <= L_) ? SCT_ : (L_ > cstart ? L_ - cstart : 0);

  auto powers = [&](float e1, float* ep) {
    ep[0] = e1;
    #pragma unroll
    for (int s = 1; s < 16; ++s) ep[s] = ep[(s - 1) >> 1] * ep[s >> 1];
  };

  // ---- pass 1: local scan from 0 ----
  float h[16];
  #pragma unroll
  for (int s = 0; s < 16; ++s) h[s] = 0.f;
  float dsum = 0.f;
  for (int k = 0; k < clen; ++k) {
    int l   = cstart + k;
    int pos = dir ? (L_ - 1 - l) : l;
    size_t grow = (size_t)(rowbase + pos);
    float dtv = bf2f(dtu[grow * DI_ + dglob]);
    float xcv = bf2f(xcu[grow * DI_ + dglob]);
    float du  = dtv * xcv;
    dsum += dtv;
    const float* brow = xd + grow * 64;
    f32x4 bq0 = *(const f32x4*)(brow + 32);
    f32x4 bq1 = *(const f32x4*)(brow + 36);
    f32x4 bq2 = *(const f32x4*)(brow + 40);
    f32x4 bq3 = *(const f32x4*)(brow + 44);
    float ep[16];
    if (fast) {
      powers(__expf(dtv * A0), ep);
    } else {
      #pragma unroll
      for (int s = 0; s < 16; ++s) ep[s] = __expf(dtv * -__expf(Arow[s]));
    }
    #pragma unroll
    for (int s = 0; s < 16; ++s) {
      float Bv = (s < 4) ? bq0[s & 3] : (s < 8) ? bq1[s & 3] : (s < 12) ? bq2[s & 3] : bq3[s & 3];
      h[s] = fmaf(ep[s], h[s], du * Bv);
    }
  }
  {
    float* hr = sH + tid * HS_;
    #pragma unroll
    for (int s = 0; s < 16; ++s) hr[s] = h[s];
    sS[tid] = dsum;
  }
  __syncthreads();

  // ---- combine: h_in = fold over previous chunks ----
  float hin[16];
  #pragma unroll
  for (int s = 0; s < 16; ++s) hin[s] = 0.f;
  for (int c = 0; c < chunk; ++c) {
    float S = sS[c * 32 + dl];
    const float* hp = sH + (c * 32 + dl) * HS_;
    float ep[16];
    if (fast) {
      powers(__expf(A0 * S), ep);
    } else {
      #pragma unroll
      for (int s = 0; s < 16; ++s) ep[s] = __expf(-__expf(Arow[s]) * S);
    }
    #pragma unroll
    for (int s = 0; s < 16; ++s)
      hin[s] = fmaf(ep[s], hin[s], hp[s]);
  }

  // ---- pass 2: scan with h_in, emit y ----
  #pragma unroll
  for (int s = 0; s < 16; ++s) h[s] = hin[s];
  for (int k = 0; k < clen; ++k) {
    int l   = cstart + k;
    int pos = dir ? (L_ - 1 - l) : l;
    size_t grow = (size_t)(rowbase + pos);
    float dtv = bf2f(dtu[grow * DI_ + dglob]);
    float xcv = bf2f(xcu[grow * DI_ + dglob]);
    float du  = dtv * xcv;
    const float* brow = xd + grow * 64;
    f32x4 bq0 = *(const f32x4*)(brow + 32);
    f32x4 bq1 = *(const f32x4*)(brow + 36);
    f32x4 bq2 = *(const f32x4*)(brow + 40);
    f32x4 bq3 = *(const f32x4*)(brow + 44);
    f32x4 cq0 = *(const f32x4*)(brow + 48);
    f32x4 cq1 = *(const f32x4*)(brow + 52);
    f32x4 cq2 = *(const f32x4*)(brow + 56);
    f32x4 cq3 = *(const f32x4*)(brow + 60);
    float ep[16];
    if (fast) {
      powers(__expf(dtv * A0), ep);
    } else {
      #pragma unroll
      for (int s = 0; s < 16; ++s) ep[s] = __expf(dtv * -__expf(Arow[s]));
    }
    float acc = 0.f;
    #pragma unroll
    for (int s = 0; s < 16; ++s) {
      float Bv = (s < 4) ? bq0[s & 3] : (s < 8) ? bq1[s & 3] : (s < 12) ? bq2[s & 3] : bq3[s & 3];
      float Cv = (s < 4) ? cq0[s & 3] : (s < 8) ? cq1[s & 3] : (s < 12) ? cq2[s & 3] : cq3[s & 3];
      h[s] = fmaf(ep[s], h[s], du * Bv);
      acc  = fmaf(h[s], Cv, acc);
    }
    y[grow * DI_ + dglob] = __float2bfloat16(fmaf(xcv, Dd, acc));
  }
}

// ---------------------------------------------------------------------------
__global__ __launch_bounds__(256) void ln_final(const float* __restrict__ x,
    const float* __restrict__ partials,
    const float* __restrict__ nw, const float* __restrict__ nb,
    float* __restrict__ out)
{
  int b = blockIdx.y, ch = blockIdx.x;
  float S = 0.f, S2 = 0.f;
  #pragma unroll
  for (int i = 0; i < 8; ++i) { S += partials[(b * 8 + i) * 2 + 0]; S2 += partials[(b * 8 + i) * 2 + 1]; }
  const float inv = 1.f / (float)(L_ * DM_);
  float mu = S * inv;
  float var = S2 * inv - mu * mu;
  float r = rsqrtf(var + 1e-5f);
  const float* xb = x + (size_t)b * (L_ * DM_);
  float* ob = out + (size_t)b * (L_ * DM_);
  int lo = ch * 12160, hi = lo + 12160;
  for (int i = lo + threadIdx.x; i < hi; i += 256) {
    float t = tanhf(xb[i]);
    ob[i] = fmaf((t - mu) * r, nw[i], nb[i]);
  }
}

// ---------------------------------------------------------------------------
extern "C" void kernel_launch(void* const* d_in, const int* in_sizes, int n_in,
                              void* d_out, int out_size, void* d_ws, size_t ws_size,
                              hipStream_t stream)
{
  const float* x            = (const float*)d_in[0];
  const void*  pc_mask      = d_in[1];
  const float* in_resize_w  = (const float*)d_in[2];
  const float* in_resize_b  = (const float*)d_in[3];
  const float* in_reset_w   = (const float*)d_in[4];
  const float* in_reset_b   = (const float*)d_in[5];
  const float* out_resize_w = (const float*)d_in[6];
  const float* out_resize_b = (const float*)d_in[7];
  const float* out_reset_w  = (const float*)d_in[8];
  const float* out_reset_b  = (const float*)d_in[9];
  const float* in_proj_w    = (const float*)d_in[10];
  const float* conv_w       = (const float*)d_in[11];
  const float* conv_b       = (const float*)d_in[12];
  const float* x_proj_w     = (const float*)d_in[13];
  const float* dt_proj_w    = (const float*)d_in[14];
  const float* dt_proj_b    = (const float*)d_in[15];
  const float* A_log        = (const float*)d_in[16];
  const float* Dv           = (const float*)d_in[17];
  const float* out_proj_w   = (const float*)d_in[18];
  const float* norm_w       = (const float*)d_in[19];
  const float* norm_b       = (const float*)d_in[20];

  // ---- workspace ----
  float* W = (float*)d_ws;
  float* maskf    = W + 0;        // 36480
  float* b_comb   = W + 36480;    // 512
  float* b_outrs  = W + 36992;    // 192
  float* xd       = W + 37184;    // 389120
  float* partials = W + 426304;   // 256
  __hip_bfloat16* BF = (__hip_bfloat16*)(W + 426560);
  __hip_bfloat16* w_inrt  = BF + 0;         // 512*192
  __hip_bfloat16* w_inpj  = BF + 98304;     // 2048*512
  __hip_bfloat16* w_xpj   = BF + 1146880;   // 64*1024
  __hip_bfloat16* w_dtpj  = BF + 1212416;   // 1024*32
  __hip_bfloat16* w_outpj = BF + 1245184;   // 512*1024
  __hip_bfloat16* w_outrs = BF + 1769472;   // 192*512
  __hip_bfloat16* w_outrt = BF + 1867776;   // 512*192
  __hip_bfloat16* w_inrsT = BF + 1966080;   // 512*192
  __hip_bfloat16* wcomb   = BF + 2064384;   // 512*512
  __hip_bfloat16* h_bf    = BF + 2326528;   // 3040*512
  __hip_bfloat16* xz_bf   = BF + 3883008;   // 3040*2048
  __hip_bfloat16* xc_bf   = BF + 10108928;  // 2*3040*1024
  __hip_bfloat16* y_bf    = BF + 16334848;  // 2*3040*1024
  __hip_bfloat16* xd_bf   = BF + 22560768;  // 6080*64
  __hip_bfloat16* dt_bf   = BF + 22949888;  // 6080*1024
  __hip_bfloat16* o_pre   = BF + 29175808;  // 3040*512
  __hip_bfloat16* o2_bf   = BF + 30732288;  // 3040*192

  float* out_ln = (float*)d_out;
  float* out_o  = (float*)d_out + (size_t)LB_ * DM_;

  dim3 blk(256);

  CvtPack2 P;
  P.d[0] = Cvt2{ in_reset_w,   w_inrt,  512, 190, 512, 192, 0 };
  P.d[1] = Cvt2{ in_proj_w,    w_inpj,  2048, 512, 2048, 512, 0 };
  P.d[2] = Cvt2{ x_proj_w,     w_xpj,   64, 1024, 64, 1024, 0 };
  P.d[3] = Cvt2{ dt_proj_w,    w_dtpj,  1024, 32, 1024, 32, 0 };
  P.d[4] = Cvt2{ out_proj_w,   w_outpj, 512, 1024, 512, 1024, 0 };
  P.d[5] = Cvt2{ out_resize_w, w_outrs, 190, 512, 192, 512, 0 };
  P.d[6] = Cvt2{ out_reset_w,  w_outrt, 512, 190, 512, 192, 0 };
  P.d[7] = Cvt2{ in_resize_w,  w_inrsT, 512, 190, 512, 192, 1 };
  cvt_all4<<<dim3(256, 11), blk, 0, stream>>>(P, pc_mask, maskf,
      in_resize_b, out_resize_b, b_outrs,
      in_reset_w, in_reset_b, b_comb, x, partials);

  // Wcomb = in_reset_w @ in_resize_w  (512x512, K=192)
  gemm32<0,false,true><<<dim3(8,16), blk, 0, stream>>>(w_inrt, 192, 512, w_inrsT, 512, nullptr, nullptr, nullptr, wcomb, 512, 192);
  // h = (x @ Wcomb^T + b_comb) * x
  gemm64<2,false,true,true><<<dim3(8,48), blk, 0, stream>>>((const __hip_bfloat16*)x, 512, 3040, wcomb, 512, b_comb, x, nullptr, h_bf, 512, 512);
  // xz = h @ in_proj_w^T
  gemm128<0,false,true><<<dim3(16,24), blk, 0, stream>>>(h_bf, 512, 3040, w_inpj, 2048, nullptr, nullptr, nullptr, xz_bf, 2048, 512);
  // conv + silu (both dirs)
  conv_silu<<<dim3(LBDI_/1024), blk, 0, stream>>>(xz_bf, conv_w, conv_b, xc_bf);
  // x_dbl = xc @ x_proj_w^T
  gemm32<0,true,true><<<dim3(1,190), blk, 0, stream>>>(xc_bf, 1024, 6080, w_xpj, 64, nullptr, nullptr, xd, xd_bf, 64, 1024);
  // dt = softplus(x_dbl[:,:32] @ dt_proj_w^T + b) -> bf16
  gemm64<3,false,true,false><<<dim3(16,95), blk, 0, stream>>>(xd_bf, 64, 6080, w_dtpj, 1024, dt_proj_b, nullptr, nullptr, dt_bf, 1024, 32);
  // selective scan (512-thread blocks, full device fill)
  scan_v12<<<dim3(32, 16, 2), dim3(512), 0, stream>>>(dt_bf, xd, xc_bf, A_log, Dv, y_bf);
  // o_pre = ((y_f+y_b)*silu(z)) @ out_proj_w^T
  gemm64_yz<<<dim3(8,48), blk, 0, stream>>>(y_bf, xz_bf, w_outpj, o_pre, 3040, 512, 1024);
  // o2 = (o_pre @ out_resize_w^T + b) * mask[l,:]
  gemm32<4,false,true><<<dim3(3,95), blk, 0, stream>>>(o_pre, 512, 3040, w_outrs, 192, b_outrs, maskf, nullptr, o2_bf, LP_, 512);
  // o = (o2 @ out_reset_w^T + b) * x  -> output 1
  gemm64<2,true,false,false><<<dim3(8,48), blk, 0, stream>>>(o2_bf, LP_, 3040, w_outrt, 512, out_reset_b, x, out_o, nullptr, 512, LP_);
  // output 0: layernorm(tanh(x))
  ln_final<<<dim3(8, B_), blk, 0, stream>>>(x, partials, norm_w, norm_b, out_ln);
}

// Round 15
// 257.984 us; speedup vs baseline: 2.2405x; 1.0436x over previous
//
#include <hip/hip_runtime.h>
#include <hip/hip_bf16.h>

#define B_    16
#define L_    190
#define LP_   192        // padded L
#define DM_   512
#define DI_   1024
#define LB_   3040       // B_*L_
#define RT_   6080       // 2*LB_ rows (dir-major)
#define LBDI_ 3112960    // LB_*DI_

typedef __attribute__((ext_vector_type(8))) short bf16x8;
typedef __attribute__((ext_vector_type(4))) float f32x4;
typedef __attribute__((ext_vector_type(4))) unsigned short u16x4;
typedef __attribute__((ext_vector_type(8))) unsigned short u16x8;

typedef const __attribute__((address_space(1))) void gvoid;
typedef __attribute__((address_space(3))) void lvoid;
#define LOAD_LDS16(g, l) __builtin_amdgcn_global_load_lds((gvoid*)(g), (lvoid*)(l), 16, 0, 0)

__device__ __forceinline__ float siluf(float v) { return v / (1.f + __expf(-v)); }
__device__ __forceinline__ float softplusf(float v) {
  return v > 0.f ? v + log1pf(__expf(-v)) : log1pf(__expf(v));
}
__device__ __forceinline__ float bf2f(unsigned short u) {
  unsigned int w = (unsigned int)u << 16; return __builtin_bit_cast(float, w);
}

// ---------------------------------------------------------------------------
// Segments 0-7: f32 -> padded bf16 (seg 7 transposed). y==8: mask + b_outrs.
// y==9: bias_comb. y==10: ln_partial.
struct Cvt2 { const float* src; __hip_bfloat16* dst; int R, C, Rp, Cp, T; };
struct CvtPack2 { Cvt2 d[8]; };

__global__ __launch_bounds__(256) void cvt_all4(CvtPack2 p,
    const void* __restrict__ pcm, float* __restrict__ maskf,
    const float* __restrict__ irb, const float* __restrict__ orb,
    float* __restrict__ b_outrs,
    const float* __restrict__ irw, const float* __restrict__ irtb,
    float* __restrict__ b_comb,
    const float* __restrict__ x, float* __restrict__ partials)
{
  if (blockIdx.y == 8) {
    __shared__ int votes[3];
    if (threadIdx.x < 3) votes[threadIdx.x] = 0;
    __syncthreads();
    if (threadIdx.x < 48) {
      int idx = threadIdx.x * 191;
      const unsigned char* p8  = (const unsigned char*)pcm;
      const unsigned int*  p32 = (const unsigned int*)pcm;
      if (p8[idx] == 1) atomicAdd(&votes[0], 1);
      unsigned int v = p32[idx];
      if (v == 1u)          atomicAdd(&votes[1], 1);
      if (v == 0x3f800000u) atomicAdd(&votes[2], 1);
    }
    __syncthreads();
    int mode = (votes[0] >= 48) ? 0 : (votes[1] >= 48 ? 1 : (votes[2] >= 48 ? 2 : 0));
    for (int i = blockIdx.x * 256 + threadIdx.x; i < L_ * LP_; i += gridDim.x * 256) {
      int r = i / LP_, c = i % LP_;
      float v = 0.f;
      if (c < L_) {
        int s = r * L_ + c;
        if (mode == 0)      v = ((const unsigned char*)pcm)[s] ? 1.f : 0.f;
        else if (mode == 1) v = ((const int*)pcm)[s] ? 1.f : 0.f;
        else                v = ((const float*)pcm)[s];
      }
      maskf[i] = v;
    }
    if (blockIdx.x == 0 && threadIdx.x < LP_)
      b_outrs[threadIdx.x] = (threadIdx.x < L_) ? orb[threadIdx.x] : 0.f;
    return;
  }
  if (blockIdx.y == 9) {
    if (blockIdx.x < 2) {
      int n = blockIdx.x * 256 + threadIdx.x;
      const float* wrow = irw + (size_t)n * L_;
      float s = 0.f;
      for (int k = 0; k < L_; ++k) s = fmaf(wrow[k], irb[k], s);
      b_comb[n] = s + irtb[n];
    }
    return;
  }
  if (blockIdx.y == 10) {
    if (blockIdx.x < 128) {
      int bb = blockIdx.x >> 3, ch = blockIdx.x & 7;
      const float* xb = x + (size_t)bb * (L_ * DM_);
      int lo = ch * 12160, hi = lo + 12160;
      float s = 0.f, s2 = 0.f;
      for (int i = lo + threadIdx.x; i < hi; i += 256) {
        float t = tanhf(xb[i]);
        s += t; s2 = fmaf(t, t, s2);
      }
      #pragma unroll
      for (int off = 32; off > 0; off >>= 1) { s += __shfl_down(s, off); s2 += __shfl_down(s2, off); }
      __shared__ float rs[4], rs2[4];
      int wid = threadIdx.x >> 6, lane = threadIdx.x & 63;
      if (lane == 0) { rs[wid] = s; rs2[wid] = s2; }
      __syncthreads();
      if (threadIdx.x == 0) {
        partials[(bb * 8 + ch) * 2 + 0] = rs[0] + rs[1] + rs[2] + rs[3];
        partials[(bb * 8 + ch) * 2 + 1] = rs2[0] + rs2[1] + rs2[2] + rs2[3];
      }
    }
    return;
  }
  Cvt2 D = p.d[blockIdx.y];
  int n = D.Rp * D.Cp;
  if (D.T) {
    for (int i = blockIdx.x * 256 + threadIdx.x; i < n; i += gridDim.x * 256) {
      int r = i / D.Cp, c = i - r * D.Cp;
      float v = (c < D.C && r < D.R) ? D.src[(size_t)c * D.R + r] : 0.f;
      D.dst[i] = __float2bfloat16(v);
    }
  } else if (D.C == D.Cp) {
    int nsrc = D.R * D.C;
    for (int i4 = (blockIdx.x * 256 + threadIdx.x) * 4; i4 < n; i4 += gridDim.x * 256 * 4) {
      __hip_bfloat16 o[4];
      if (i4 + 3 < nsrc) {
        f32x4 v = *(const f32x4*)(D.src + i4);
        #pragma unroll
        for (int q = 0; q < 4; ++q) o[q] = __float2bfloat16(v[q]);
      } else {
        #pragma unroll
        for (int q = 0; q < 4; ++q) { int i = i4 + q; o[q] = __float2bfloat16(i < nsrc ? D.src[i] : 0.f); }
      }
      *(u16x4*)(D.dst + i4) = *(u16x4*)o;
    }
  } else {
    for (int i = blockIdx.x * 256 + threadIdx.x; i < n; i += gridDim.x * 256) {
      int r = i / D.Cp, c = i - r * D.Cp;
      float v = (r < D.R && c < D.C) ? D.src[(size_t)r * D.C + c] : 0.f;
      D.dst[i] = __float2bfloat16(v);
    }
  }
}

// ---------------------------------------------------------------------------
// MFMA GEMM 128x128 (4 waves x 64x64).
template<int EPI, bool OF32, bool OBF>
__global__ __launch_bounds__(256) void gemm128(
    const __hip_bfloat16* __restrict__ A, int lda, int M,
    const __hip_bfloat16* __restrict__ Bw, int Brows,
    const float* __restrict__ bias, const float* __restrict__ aux,
    float* __restrict__ Cf, __hip_bfloat16* __restrict__ Cb,
    int N, int K)
{
  __shared__ bf16x8 SA[2][512];
  __shared__ bf16x8 SB[2][512];
  const int tid = threadIdx.x;
  const int wave = tid >> 6, lane = tid & 63;
  const int m0 = blockIdx.y * 128, n0 = blockIdx.x * 128;
  const int wm = (wave >> 1) * 64, wn = (wave & 1) * 64;
  const int l15 = lane & 15, lkb = lane >> 4;

  f32x4 acc[4][4] = {};

  auto stage = [&](int bsel, int k0) {
    #pragma unroll
    for (int it = 0; it < 2; ++it) {
      int c = it * 256 + tid;
      int row = c & 127, kb = c >> 7;
      int ar = m0 + row; ar = ar < M ? ar : M - 1;
      const __hip_bfloat16* ga = A + (size_t)ar * lda + (k0 + kb * 8);
      LOAD_LDS16(ga, &SA[bsel][it * 256 + wave * 64]);
      int br = n0 + row; br = br < Brows ? br : Brows - 1;
      const __hip_bfloat16* gb = Bw + (size_t)br * K + (k0 + kb * 8);
      LOAD_LDS16(gb, &SB[bsel][it * 256 + wave * 64]);
    }
  };

  const int nk = K >> 5;
  stage(0, 0);
  __syncthreads();
  int buf = 0;
  for (int kt = 0; kt < nk; ++kt) {
    if (kt + 1 < nk) stage(buf ^ 1, (kt + 1) * 32);
    bf16x8 af[4], bq[4];
    #pragma unroll
    for (int f = 0; f < 4; ++f) {
      af[f] = SA[buf][lkb * 128 + wm + f * 16 + l15];
      bq[f] = SB[buf][lkb * 128 + wn + f * 16 + l15];
    }
    #pragma unroll
    for (int i = 0; i < 4; ++i)
      #pragma unroll
      for (int j = 0; j < 4; ++j)
        acc[i][j] = __builtin_amdgcn_mfma_f32_16x16x32_bf16(af[i], bq[j], acc[i][j], 0, 0, 0);
    __syncthreads();
    buf ^= 1;
  }

  #pragma unroll
  for (int i = 0; i < 4; ++i) {
    int r0 = m0 + wm + i * 16 + (lkb << 2);
    #pragma unroll
    for (int j = 0; j < 4; ++j) {
      int col = n0 + wn + j * 16 + l15;
      if (col >= N) continue;
      #pragma unroll
      for (int r = 0; r < 4; ++r) {
        int row = r0 + r;
        if (row >= M) continue;
        float v = acc[i][j][r];
        if (EPI >= 1) v += bias[col];
        if (EPI == 2) v *= aux[(size_t)row * N + col];
        if (EPI == 3) v = softplusf(v);
        if (EPI == 4) v *= aux[(size_t)(row % L_) * N + col];
        if (OF32) Cf[(size_t)row * N + col] = v;
        if (OBF)  Cb[(size_t)row * N + col] = __float2bfloat16(v);
      }
    }
  }
}

// ---------------------------------------------------------------------------
// MFMA GEMM 64x64 (4 waves x 32x32). AF32: A is f32, reg-staged + converted.
template<int EPI, bool OF32, bool OBF, bool AF32>
__global__ __launch_bounds__(256) void gemm64(
    const __hip_bfloat16* __restrict__ A, int lda, int M,
    const __hip_bfloat16* __restrict__ Bw, int Brows,
    const float* __restrict__ bias, const float* __restrict__ aux,
    float* __restrict__ Cf, __hip_bfloat16* __restrict__ Cb,
    int N, int K)
{
  __shared__ bf16x8 SA[2][256];
  __shared__ bf16x8 SB[2][256];
  const int tid = threadIdx.x;
  const int wave = tid >> 6, lane = tid & 63;
  const int m0 = blockIdx.y * 64, n0 = blockIdx.x * 64;
  const int wm = (wave >> 1) * 32, wn = (wave & 1) * 32;
  const int l15 = lane & 15, lkb = lane >> 4;

  f32x4 acc[2][2] = {};

  auto stage = [&](int bsel, int k0) {
    int row = tid & 63, kb = tid >> 6;
    int ar = m0 + row; ar = ar < M ? ar : M - 1;
    if (AF32) {
      const float* ga = (const float*)A + (size_t)ar * lda + (k0 + kb * 8);
      f32x4 v0 = *(const f32x4*)ga;
      f32x4 v1 = *(const f32x4*)(ga + 4);
      __hip_bfloat16 o[8];
      #pragma unroll
      for (int q = 0; q < 4; ++q) { o[q] = __float2bfloat16(v0[q]); o[q + 4] = __float2bfloat16(v1[q]); }
      SA[bsel][wave * 64 + row] = *(bf16x8*)o;
    } else {
      const __hip_bfloat16* ga = A + (size_t)ar * lda + (k0 + kb * 8);
      LOAD_LDS16(ga, &SA[bsel][wave * 64]);
    }
    int br = n0 + row; br = br < Brows ? br : Brows - 1;
    const __hip_bfloat16* gb = Bw + (size_t)br * K + (k0 + kb * 8);
    LOAD_LDS16(gb, &SB[bsel][wave * 64]);
  };

  const int nk = K >> 5;
  stage(0, 0);
  __syncthreads();
  int buf = 0;
  for (int kt = 0; kt < nk; ++kt) {
    if (kt + 1 < nk) stage(buf ^ 1, (kt + 1) * 32);
    bf16x8 af[2], bq[2];
    #pragma unroll
    for (int f = 0; f < 2; ++f) {
      af[f] = SA[buf][lkb * 64 + wm + f * 16 + l15];
      bq[f] = SB[buf][lkb * 64 + wn + f * 16 + l15];
    }
    #pragma unroll
    for (int i = 0; i < 2; ++i)
      #pragma unroll
      for (int j = 0; j < 2; ++j)
        acc[i][j] = __builtin_amdgcn_mfma_f32_16x16x32_bf16(af[i], bq[j], acc[i][j], 0, 0, 0);
    __syncthreads();
    buf ^= 1;
  }

  #pragma unroll
  for (int i = 0; i < 2; ++i) {
    int r0 = m0 + wm + i * 16 + (lkb << 2);
    #pragma unroll
    for (int j = 0; j < 2; ++j) {
      int col = n0 + wn + j * 16 + l15;
      if (col >= N) continue;
      #pragma unroll
      for (int r = 0; r < 4; ++r) {
        int row = r0 + r;
        if (row >= M) continue;
        float v = acc[i][j][r];
        if (EPI >= 1) v += bias[col];
        if (EPI == 2) v *= aux[(size_t)row * N + col];
        if (EPI == 3) v = softplusf(v);
        if (EPI == 4) v *= aux[(size_t)(row % L_) * N + col];
        if (OF32) Cf[(size_t)row * N + col] = v;
        if (OBF)  Cb[(size_t)row * N + col] = __float2bfloat16(v);
      }
    }
  }
}

// ---------------------------------------------------------------------------
// MFMA GEMM 32x64 (4 waves x 16x32).
template<int EPI, bool OF32, bool OBF>
__global__ __launch_bounds__(256) void gemm32(
    const __hip_bfloat16* __restrict__ A, int lda, int M,
    const __hip_bfloat16* __restrict__ Bw, int Brows,
    const float* __restrict__ bias, const float* __restrict__ aux,
    float* __restrict__ Cf, __hip_bfloat16* __restrict__ Cb,
    int N, int K)
{
  __shared__ bf16x8 SA[2][128];
  __shared__ bf16x8 SB[2][256];
  const int tid = threadIdx.x;
  const int wave = tid >> 6, lane = tid & 63;
  const int m0 = blockIdx.y * 32, n0 = blockIdx.x * 64;
  const int wm = (wave >> 1) * 16, wn = (wave & 1) * 32;
  const int l15 = lane & 15, lkb = lane >> 4;

  f32x4 acc[2] = {};

  auto stage = [&](int bsel, int k0) {
    if (wave < 2) {
      int row = tid & 31, kb = tid >> 5;
      int ar = m0 + row; ar = ar < M ? ar : M - 1;
      const __hip_bfloat16* ga = A + (size_t)ar * lda + (k0 + kb * 8);
      LOAD_LDS16(ga, &SA[bsel][wave * 64]);
    } else {
      int t2 = tid - 128;
      {
        int row = t2 & 63, kb = t2 >> 6;
        int br = n0 + row; br = br < Brows ? br : Brows - 1;
        const __hip_bfloat16* gb = Bw + (size_t)br * K + (k0 + kb * 8);
        LOAD_LDS16(gb, &SB[bsel][(wave - 2) * 64]);
      }
      {
        int s1 = t2 + 128;
        int row = s1 & 63, kb = s1 >> 6;
        int br = n0 + row; br = br < Brows ? br : Brows - 1;
        const __hip_bfloat16* gb = Bw + (size_t)br * K + (k0 + kb * 8);
        LOAD_LDS16(gb, &SB[bsel][128 + (wave - 2) * 64]);
      }
    }
  };

  const int nk = K >> 5;
  stage(0, 0);
  __syncthreads();
  int buf = 0;
  for (int kt = 0; kt < nk; ++kt) {
    if (kt + 1 < nk) stage(buf ^ 1, (kt + 1) * 32);
    bf16x8 af = SA[buf][lkb * 32 + wm + l15];
    bf16x8 b0 = SB[buf][lkb * 64 + wn + l15];
    bf16x8 b1 = SB[buf][lkb * 64 + wn + 16 + l15];
    acc[0] = __builtin_amdgcn_mfma_f32_16x16x32_bf16(af, b0, acc[0], 0, 0, 0);
    acc[1] = __builtin_amdgcn_mfma_f32_16x16x32_bf16(af, b1, acc[1], 0, 0, 0);
    __syncthreads();
    buf ^= 1;
  }

  int r0 = m0 + wm + (lkb << 2);
  #pragma unroll
  for (int j = 0; j < 2; ++j) {
    int col = n0 + wn + j * 16 + l15;
    if (col >= N) continue;
    #pragma unroll
    for (int r = 0; r < 4; ++r) {
      int row = r0 + r;
      if (row >= M) continue;
      float v = acc[j][r];
      if (EPI >= 1) v += bias[col];
      if (EPI == 2) v *= aux[(size_t)row * N + col];
      if (EPI == 3) v = softplusf(v);
      if (EPI == 4) v *= aux[(size_t)(row % L_) * N + col];
      if (OF32) Cf[(size_t)row * N + col] = v;
      if (OBF)  Cb[(size_t)row * N + col] = __float2bfloat16(v);
    }
  }
}

// ---------------------------------------------------------------------------
// out_proj GEMM with fused A = (y_f+y_b)*silu(z).
__global__ __launch_bounds__(256) void gemm64_yz(
    const __hip_bfloat16* __restrict__ Y,
    const __hip_bfloat16* __restrict__ Xz,
    const __hip_bfloat16* __restrict__ Bw,
    __hip_bfloat16* __restrict__ Cb,
    int M, int N, int K)
{
  __shared__ bf16x8 SA[2][256];
  __shared__ bf16x8 SB[2][256];
  const int tid = threadIdx.x;
  const int wave = tid >> 6, lane = tid & 63;
  const int m0 = blockIdx.y * 64, n0 = blockIdx.x * 64;
  const int wm = (wave >> 1) * 32, wn = (wave & 1) * 32;
  const int l15 = lane & 15, lkb = lane >> 4;

  f32x4 acc[2][2] = {};

  auto stage = [&](int bsel, int k0) {
    int row = tid & 63, kb = tid >> 6;
    int ar = m0 + row; ar = ar < M ? ar : M - 1;
    size_t o = (size_t)ar * DI_ + (k0 + kb * 8);
    u16x8 f8 = *(const u16x8*)(Y + o);
    u16x8 g8 = *(const u16x8*)(Y + LBDI_ + o);
    u16x8 z8 = *(const u16x8*)(Xz + (size_t)ar * (2 * DI_) + DI_ + (k0 + kb * 8));
    unsigned short av[8];
    #pragma unroll
    for (int q = 0; q < 8; ++q) {
      float v = (bf2f(f8[q]) + bf2f(g8[q])) * siluf(bf2f(z8[q]));
      av[q] = __bfloat16_as_ushort(__float2bfloat16(v));
    }
    SA[bsel][wave * 64 + row] = *(bf16x8*)av;
    int br = n0 + row; br = br < N ? br : N - 1;
    const __hip_bfloat16* gb = Bw + (size_t)br * K + (k0 + kb * 8);
    LOAD_LDS16(gb, &SB[bsel][wave * 64]);
  };

  const int nk = K >> 5;
  stage(0, 0);
  __syncthreads();
  int buf = 0;
  for (int kt = 0; kt < nk; ++kt) {
    if (kt + 1 < nk) stage(buf ^ 1, (kt + 1) * 32);
    bf16x8 af[2], bq[2];
    #pragma unroll
    for (int f = 0; f < 2; ++f) {
      af[f] = SA[buf][lkb * 64 + wm + f * 16 + l15];
      bq[f] = SB[buf][lkb * 64 + wn + f * 16 + l15];
    }
    #pragma unroll
    for (int i = 0; i < 2; ++i)
      #pragma unroll
      for (int j = 0; j < 2; ++j)
        acc[i][j] = __builtin_amdgcn_mfma_f32_16x16x32_bf16(af[i], bq[j], acc[i][j], 0, 0, 0);
    __syncthreads();
    buf ^= 1;
  }

  #pragma unroll
  for (int i = 0; i < 2; ++i) {
    int r0 = m0 + wm + i * 16 + (lkb << 2);
    #pragma unroll
    for (int j = 0; j < 2; ++j) {
      int col = n0 + wn + j * 16 + l15;
      if (col >= N) continue;
      #pragma unroll
      for (int r = 0; r < 4; ++r) {
        int row = r0 + r;
        if (row >= M) continue;
        Cb[(size_t)row * N + col] = __float2bfloat16(acc[i][j][r]);
      }
    }
  }
}

// ---------------------------------------------------------------------------
// Depthwise conv(k=4) + bias + silu, both directions; 4 channels per thread.
__global__ __launch_bounds__(256) void conv_silu(
    const __hip_bfloat16* __restrict__ xz, const float* __restrict__ w,
    const float* __restrict__ cb, __hip_bfloat16* __restrict__ xcbf)
{
  int t = blockIdx.x * 256 + threadIdx.x;
  int c4 = (t & (DI_ / 4 - 1)) * 4;
  int bl = t >> 8;
  int l = bl % L_;
  int b = bl / L_;
  const __hip_bfloat16* base = xz + (size_t)b * L_ * (2 * DI_) + c4;
  float xr[7][4];
  #pragma unroll
  for (int j = 0; j < 7; ++j) {
    int gl = l + j - 3;
    if (gl >= 0 && gl < L_) {
      u16x4 v = *(const u16x4*)(base + (size_t)gl * (2 * DI_));
      #pragma unroll
      for (int q = 0; q < 4; ++q) xr[j][q] = bf2f(v[q]);
    } else {
      #pragma unroll
      for (int q = 0; q < 4; ++q) xr[j][q] = 0.f;
    }
  }
  __hip_bfloat16 of[4], ob[4];
  #pragma unroll
  for (int q = 0; q < 4; ++q) {
    int c = c4 + q;
    float w0 = w[c * 4], w1 = w[c * 4 + 1], w2 = w[c * 4 + 2], w3 = w[c * 4 + 3];
    float bias = cb[c];
    float sf = fmaf(w0, xr[0][q], fmaf(w1, xr[1][q], fmaf(w2, xr[2][q], fmaf(w3, xr[3][q], bias))));
    float sb = fmaf(w0, xr[6][q], fmaf(w1, xr[5][q], fmaf(w2, xr[4][q], fmaf(w3, xr[3][q], bias))));
    of[q] = __float2bfloat16(siluf(sf));
    ob[q] = __float2bfloat16(siluf(sb));
  }
  size_t o = (size_t)bl * DI_ + c4;
  *(u16x4*)(xcbf + o)         = *(u16x4*)of;
  *(u16x4*)(xcbf + LBDI_ + o) = *(u16x4*)ob;
}

// ---------------------------------------------------------------------------
// Selective scan v13: v12 structure + software-pipelined dt/xc/B prefetch
// (scalars + one f32x4 quad set only — no per-step arrays).
#define SCT_ 12
#define HS_  17
__global__ __launch_bounds__(512) void scan_v13(
    const __hip_bfloat16* __restrict__ dtb, // [RT_][DI_] bf16
    const float* __restrict__ xd,           // [RT_][64]  f32
    const __hip_bfloat16* __restrict__ xc,  // [RT_][DI_] bf16
    const float* __restrict__ A_log, const float* __restrict__ Dv,
    __hip_bfloat16* __restrict__ y)         // [RT_][DI_] bf16
{
  __shared__ float sH[512 * HS_];    // 34816 B
  __shared__ float sS[512];          //  2048 B

  const int tid   = threadIdx.x;
  const int dl    = tid & 31;
  const int chunk = tid >> 5;        // 0..15
  const int dglob = blockIdx.x * 32 + dl;
  const int b     = blockIdx.y;
  const int dir   = blockIdx.z;
  const int rowbase = dir * LB_ + b * L_;
  const unsigned short* xcu = (const unsigned short*)xc;
  const unsigned short* dtu = (const unsigned short*)dtb;
  const float* Arow = A_log + dglob * 16;

  const float A0 = -__expf(Arow[0]);
  bool fast = true;
  #pragma unroll
  for (int s = 1; s < 16; ++s) {
    float As = -__expf(Arow[s]);
    fast = fast && (fabsf(As - (float)(s + 1) * A0) <= 1e-4f * (float)(s + 1));
  }
  const float Dd = Dv[dglob];

  const int cstart = chunk * SCT_;
  const int clen = (cstart + SCT_ <= L_) ? SCT_ : (L_ > cstart ? L_ - cstart : 0);

  auto powers = [&](float e1, float* ep) {
    ep[0] = e1;
    #pragma unroll
    for (int s = 1; s < 16; ++s) ep[s] = ep[(s - 1) >> 1] * ep[s >> 1];
  };
  auto growAt = [&](int k) -> size_t {
    int l = cstart + k;
    int pos = dir ? (L_ - 1 - l) : l;
    return (size_t)(rowbase + pos);
  };

  // ---- pass 1: local scan from 0 (pipelined) ----
  float h[16];
  #pragma unroll
  for (int s = 0; s < 16; ++s) h[s] = 0.f;
  float dsum = 0.f;
  if (clen > 0) {
    size_t g = growAt(0);
    float dtv = bf2f(dtu[g * DI_ + dglob]);
    float xcv = bf2f(xcu[g * DI_ + dglob]);
    f32x4 bq0 = *(const f32x4*)(xd + g * 64 + 32);
    f32x4 bq1 = *(const f32x4*)(xd + g * 64 + 36);
    f32x4 bq2 = *(const f32x4*)(xd + g * 64 + 40);
    f32x4 bq3 = *(const f32x4*)(xd + g * 64 + 44);
    for (int k = 0; k < clen; ++k) {
      int kn = (k + 1 < clen) ? k + 1 : k;
      size_t gn = growAt(kn);
      float ndt = bf2f(dtu[gn * DI_ + dglob]);
      float nxc = bf2f(xcu[gn * DI_ + dglob]);
      f32x4 nb0 = *(const f32x4*)(xd + gn * 64 + 32);
      f32x4 nb1 = *(const f32x4*)(xd + gn * 64 + 36);
      f32x4 nb2 = *(const f32x4*)(xd + gn * 64 + 40);
      f32x4 nb3 = *(const f32x4*)(xd + gn * 64 + 44);
      float du = dtv * xcv;
      dsum += dtv;
      float ep[16];
      if (fast) {
        powers(__expf(dtv * A0), ep);
      } else {
        #pragma unroll
        for (int s = 0; s < 16; ++s) ep[s] = __expf(dtv * -__expf(Arow[s]));
      }
      #pragma unroll
      for (int s = 0; s < 16; ++s) {
        float Bv = (s < 4) ? bq0[s & 3] : (s < 8) ? bq1[s & 3] : (s < 12) ? bq2[s & 3] : bq3[s & 3];
        h[s] = fmaf(ep[s], h[s], du * Bv);
      }
      dtv = ndt; xcv = nxc; bq0 = nb0; bq1 = nb1; bq2 = nb2; bq3 = nb3;
    }
  }
  {
    float* hr = sH + tid * HS_;
    #pragma unroll
    for (int s = 0; s < 16; ++s) hr[s] = h[s];
    sS[tid] = dsum;
  }
  __syncthreads();

  // ---- combine: h_in = fold over previous chunks ----
  float hin[16];
  #pragma unroll
  for (int s = 0; s < 16; ++s) hin[s] = 0.f;
  for (int c = 0; c < chunk; ++c) {
    float S = sS[c * 32 + dl];
    const float* hp = sH + (c * 32 + dl) * HS_;
    float ep[16];
    if (fast) {
      powers(__expf(A0 * S), ep);
    } else {
      #pragma unroll
      for (int s = 0; s < 16; ++s) ep[s] = __expf(-__expf(Arow[s]) * S);
    }
    #pragma unroll
    for (int s = 0; s < 16; ++s)
      hin[s] = fmaf(ep[s], hin[s], hp[s]);
  }

  // ---- pass 2: scan with h_in, emit y (pipelined dt/xc) ----
  #pragma unroll
  for (int s = 0; s < 16; ++s) h[s] = hin[s];
  if (clen > 0) {
    size_t g = growAt(0);
    float dtv = bf2f(dtu[g * DI_ + dglob]);
    float xcv = bf2f(xcu[g * DI_ + dglob]);
    for (int k = 0; k < clen; ++k) {
      int kn = (k + 1 < clen) ? k + 1 : k;
      size_t gn = growAt(kn);
      float ndt = bf2f(dtu[gn * DI_ + dglob]);
      float nxc = bf2f(xcu[gn * DI_ + dglob]);
      size_t grow = growAt(k);
      const float* brow = xd + grow * 64;
      f32x4 bq0 = *(const f32x4*)(brow + 32);
      f32x4 bq1 = *(const f32x4*)(brow + 36);
      f32x4 bq2 = *(const f32x4*)(brow + 40);
      f32x4 bq3 = *(const f32x4*)(brow + 44);
      f32x4 cq0 = *(const f32x4*)(brow + 48);
      f32x4 cq1 = *(const f32x4*)(brow + 52);
      f32x4 cq2 = *(const f32x4*)(brow + 56);
      f32x4 cq3 = *(const f32x4*)(brow + 60);
      float du = dtv * xcv;
      float ep[16];
      if (fast) {
        powers(__expf(dtv * A0), ep);
      } else {
        #pragma unroll
        for (int s = 0; s < 16; ++s) ep[s] = __expf(dtv * -__expf(Arow[s]));
      }
      float acc = 0.f;
      #pragma unroll
      for (int s = 0; s < 16; ++s) {
        float Bv = (s < 4) ? bq0[s & 3] : (s < 8) ? bq1[s & 3] : (s < 12) ? bq2[s & 3] : bq3[s & 3];
        float Cv = (s < 4) ? cq0[s & 3] : (s < 8) ? cq1[s & 3] : (s < 12) ? cq2[s & 3] : cq3[s & 3];
        h[s] = fmaf(ep[s], h[s], du * Bv);
        acc  = fmaf(h[s], Cv, acc);
      }
      y[grow * DI_ + dglob] = __float2bfloat16(fmaf(xcv, Dd, acc));
      dtv = ndt; xcv = nxc;
    }
  }
}

// ---------------------------------------------------------------------------
__global__ __launch_bounds__(256) void ln_final(const float* __restrict__ x,
    const float* __restrict__ partials,
    const float* __restrict__ nw, const float* __restrict__ nb,
    float* __restrict__ out)
{
  int b = blockIdx.y, ch = blockIdx.x;
  float S = 0.f, S2 = 0.f;
  #pragma unroll
  for (int i = 0; i < 8; ++i) { S += partials[(b * 8 + i) * 2 + 0]; S2 += partials[(b * 8 + i) * 2 + 1]; }
  const float inv = 1.f / (float)(L_ * DM_);
  float mu = S * inv;
  float var = S2 * inv - mu * mu;
  float r = rsqrtf(var + 1e-5f);
  const float* xb = x + (size_t)b * (L_ * DM_);
  float* ob = out + (size_t)b * (L_ * DM_);
  int lo = ch * 12160, hi = lo + 12160;
  for (int i = lo + threadIdx.x; i < hi; i += 256) {
    float t = tanhf(xb[i]);
    ob[i] = fmaf((t - mu) * r, nw[i], nb[i]);
  }
}

// ---------------------------------------------------------------------------
extern "C" void kernel_launch(void* const* d_in, const int* in_sizes, int n_in,
                              void* d_out, int out_size, void* d_ws, size_t ws_size,
                              hipStream_t stream)
{
  const float* x            = (const float*)d_in[0];
  const void*  pc_mask      = d_in[1];
  const float* in_resize_w  = (const float*)d_in[2];
  const float* in_resize_b  = (const float*)d_in[3];
  const float* in_reset_w   = (const float*)d_in[4];
  const float* in_reset_b   = (const float*)d_in[5];
  const float* out_resize_w = (const float*)d_in[6];
  const float* out_resize_b = (const float*)d_in[7];
  const float* out_reset_w  = (const float*)d_in[8];
  const float* out_reset_b  = (const float*)d_in[9];
  const float* in_proj_w    = (const float*)d_in[10];
  const float* conv_w       = (const float*)d_in[11];
  const float* conv_b       = (const float*)d_in[12];
  const float* x_proj_w     = (const float*)d_in[13];
  const float* dt_proj_w    = (const float*)d_in[14];
  const float* dt_proj_b    = (const float*)d_in[15];
  const float* A_log        = (const float*)d_in[16];
  const float* Dv           = (const float*)d_in[17];
  const float* out_proj_w   = (const float*)d_in[18];
  const float* norm_w       = (const float*)d_in[19];
  const float* norm_b       = (const float*)d_in[20];

  // ---- workspace ----
  float* W = (float*)d_ws;
  float* maskf    = W + 0;        // 36480
  float* b_comb   = W + 36480;    // 512
  float* b_outrs  = W + 36992;    // 192
  float* xd       = W + 37184;    // 389120
  float* partials = W + 426304;   // 256
  __hip_bfloat16* BF = (__hip_bfloat16*)(W + 426560);
  __hip_bfloat16* w_inrt  = BF + 0;         // 512*192
  __hip_bfloat16* w_inpj  = BF + 98304;     // 2048*512
  __hip_bfloat16* w_xpj   = BF + 1146880;   // 64*1024
  __hip_bfloat16* w_dtpj  = BF + 1212416;   // 1024*32
  __hip_bfloat16* w_outpj = BF + 1245184;   // 512*1024
  __hip_bfloat16* w_outrs = BF + 1769472;   // 192*512
  __hip_bfloat16* w_outrt = BF + 1867776;   // 512*192
  __hip_bfloat16* w_inrsT = BF + 1966080;   // 512*192
  __hip_bfloat16* wcomb   = BF + 2064384;   // 512*512
  __hip_bfloat16* h_bf    = BF + 2326528;   // 3040*512
  __hip_bfloat16* xz_bf   = BF + 3883008;   // 3040*2048
  __hip_bfloat16* xc_bf   = BF + 10108928;  // 2*3040*1024
  __hip_bfloat16* y_bf    = BF + 16334848;  // 2*3040*1024
  __hip_bfloat16* xd_bf   = BF + 22560768;  // 6080*64
  __hip_bfloat16* dt_bf   = BF + 22949888;  // 6080*1024
  __hip_bfloat16* o_pre   = BF + 29175808;  // 3040*512
  __hip_bfloat16* o2_bf   = BF + 30732288;  // 3040*192

  float* out_ln = (float*)d_out;
  float* out_o  = (float*)d_out + (size_t)LB_ * DM_;

  dim3 blk(256);

  CvtPack2 P;
  P.d[0] = Cvt2{ in_reset_w,   w_inrt,  512, 190, 512, 192, 0 };
  P.d[1] = Cvt2{ in_proj_w,    w_inpj,  2048, 512, 2048, 512, 0 };
  P.d[2] = Cvt2{ x_proj_w,     w_xpj,   64, 1024, 64, 1024, 0 };
  P.d[3] = Cvt2{ dt_proj_w,    w_dtpj,  1024, 32, 1024, 32, 0 };
  P.d[4] = Cvt2{ out_proj_w,   w_outpj, 512, 1024, 512, 1024, 0 };
  P.d[5] = Cvt2{ out_resize_w, w_outrs, 190, 512, 192, 512, 0 };
  P.d[6] = Cvt2{ out_reset_w,  w_outrt, 512, 190, 512, 192, 0 };
  P.d[7] = Cvt2{ in_resize_w,  w_inrsT, 512, 190, 512, 192, 1 };
  cvt_all4<<<dim3(256, 11), blk, 0, stream>>>(P, pc_mask, maskf,
      in_resize_b, out_resize_b, b_outrs,
      in_reset_w, in_reset_b, b_comb, x, partials);

  // Wcomb = in_reset_w @ in_resize_w  (512x512, K=192)
  gemm32<0,false,true><<<dim3(8,16), blk, 0, stream>>>(w_inrt, 192, 512, w_inrsT, 512, nullptr, nullptr, nullptr, wcomb, 512, 192);
  // h = (x @ Wcomb^T + b_comb) * x
  gemm64<2,false,true,true><<<dim3(8,48), blk, 0, stream>>>((const __hip_bfloat16*)x, 512, 3040, wcomb, 512, b_comb, x, nullptr, h_bf, 512, 512);
  // xz = h @ in_proj_w^T
  gemm128<0,false,true><<<dim3(16,24), blk, 0, stream>>>(h_bf, 512, 3040, w_inpj, 2048, nullptr, nullptr, nullptr, xz_bf, 2048, 512);
  // conv + silu (both dirs)
  conv_silu<<<dim3(LBDI_/1024), blk, 0, stream>>>(xz_bf, conv_w, conv_b, xc_bf);
  // x_dbl = xc @ x_proj_w^T
  gemm32<0,true,true><<<dim3(1,190), blk, 0, stream>>>(xc_bf, 1024, 6080, w_xpj, 64, nullptr, nullptr, xd, xd_bf, 64, 1024);
  // dt = softplus(x_dbl[:,:32] @ dt_proj_w^T + b) -> bf16
  gemm64<3,false,true,false><<<dim3(16,95), blk, 0, stream>>>(xd_bf, 64, 6080, w_dtpj, 1024, dt_proj_b, nullptr, nullptr, dt_bf, 1024, 32);
  // selective scan (pipelined loads)
  scan_v13<<<dim3(32, 16, 2), dim3(512), 0, stream>>>(dt_bf, xd, xc_bf, A_log, Dv, y_bf);
  // o_pre = ((y_f+y_b)*silu(z)) @ out_proj_w^T
  gemm64_yz<<<dim3(8,48), blk, 0, stream>>>(y_bf, xz_bf, w_outpj, o_pre, 3040, 512, 1024);
  // o2 = (o_pre @ out_resize_w^T + b) * mask[l,:]
  gemm32<4,false,true><<<dim3(3,95), blk, 0, stream>>>(o_pre, 512, 3040, w_outrs, 192, b_outrs, maskf, nullptr, o2_bf, LP_, 512);
  // o = (o2 @ out_reset_w^T + b) * x  -> output 1
  gemm64<2,true,false,false><<<dim3(8,48), blk, 0, stream>>>(o2_bf, LP_, 3040, w_outrt, 512, out_reset_b, x, out_o, nullptr, 512, LP_);
  // output 0: layernorm(tanh(x))
  ln_final<<<dim3(8, B_), blk, 0, stream>>>(x, partials, norm_w, norm_b, out_ln);
}